// Round 1
// baseline (375.096 us; speedup 1.0000x reference)
//
#include <hip/hip_runtime.h>
#include <math.h>

// Problem constants (fixed shapes)
namespace {
constexpr int Dm  = 512;
constexpr int Bn  = 16;
constexpr int LQn = 32;
constexpr int LKn = 256;
constexpr int Hn  = 8;
constexpr int NBL = Bn * LQn;  // 512 (b,l) rows
constexpr int NBK = Bn * LKn;  // 4096 (b,k) rows
constexpr float LN_EPS = 1e-5f;

__device__ __forceinline__ float4 ld4(const float* p) { return *reinterpret_cast<const float4*>(p); }
__device__ __forceinline__ void st4(float* p, float4 v) { *reinterpret_cast<float4*>(p) = v; }
__device__ __forceinline__ float4 f4_fma(float4 a, float4 b, float4 c) {
  return make_float4(fmaf(a.x, b.x, c.x), fmaf(a.y, b.y, c.y), fmaf(a.z, b.z, c.z), fmaf(a.w, b.w, c.w));
}
__device__ __forceinline__ float4 f4_add(float4 a, float4 b) {
  return make_float4(a.x + b.x, a.y + b.y, a.z + b.z, a.w + b.w);
}
__device__ __forceinline__ float4 f4_subs(float4 a, float s) {
  return make_float4(a.x - s, a.y - s, a.z - s, a.w - s);
}
__device__ __forceinline__ float4 f4_muls(float4 a, float s) {
  return make_float4(a.x * s, a.y * s, a.z * s, a.w * s);
}
__device__ __forceinline__ float f4_hsum(float4 a) { return (a.x + a.y) + (a.z + a.w); }
__device__ __forceinline__ float f4_dot(float4 a, float4 b) {
  return fmaf(a.x, b.x, fmaf(a.y, b.y, fmaf(a.z, b.z, a.w * b.w)));
}

// ---------------------------------------------------------------------------
// Generic row-tiled matvec: out[r,j] = sum_d X[r,d]*W[j,d] (+bias)
// POST 0: plain store to out0 (row stride C_total)
// POST 1: tanh, split at C_total/2 -> out0 (gammas) / out1 (betas)
// ---------------------------------------------------------------------------
template <int ROWS, int POST>
__global__ __launch_bounds__(256) void proj_kernel(
    const float* __restrict__ X, const float* __restrict__ W,
    const float* __restrict__ bias,
    float* __restrict__ out0, float* __restrict__ out1,
    int C_total, int cols_per_block) {
  __shared__ float Xs[ROWS][Dm];
  const int r0 = blockIdx.x * ROWS;
  const int tid = threadIdx.x;
  for (int i = tid; i < ROWS * Dm; i += 256) {
    Xs[i / Dm][i % Dm] = X[(size_t)(r0 + i / Dm) * Dm + (i % Dm)];
  }
  __syncthreads();
  const int j0 = blockIdx.y * cols_per_block;
  for (int j = j0 + tid; j < j0 + cols_per_block; j += 256) {
    float acc[ROWS];
#pragma unroll
    for (int r = 0; r < ROWS; ++r) acc[r] = 0.f;
    const float* wrow = W + (size_t)j * Dm;
    for (int d = 0; d < Dm; d += 4) {
      const float4 w = ld4(wrow + d);
#pragma unroll
      for (int r = 0; r < ROWS; ++r) {
        acc[r] += Xs[r][d] * w.x + Xs[r][d + 1] * w.y + Xs[r][d + 2] * w.z + Xs[r][d + 3] * w.w;
      }
    }
    const float bb = bias ? bias[j] : 0.f;
#pragma unroll
    for (int r = 0; r < ROWS; ++r) {
      float v = acc[r] + bb;
      if (POST == 1) {
        v = tanhf(v);
        const int Ch = C_total >> 1;
        if (j < Ch) out0[(size_t)(r0 + r) * Ch + j] = v;
        else        out1[(size_t)(r0 + r) * Ch + (j - Ch)] = v;
      } else {
        out0[(size_t)(r0 + r) * C_total + j] = v;
      }
    }
  }
}

// ---------------------------------------------------------------------------
// cond_base = LayerNorm(k @ Wvp.T + bvp)  — 8 rows/block, full 512 cols
// ---------------------------------------------------------------------------
__global__ __launch_bounds__(256) void lnproj_kernel(
    const float* __restrict__ X, const float* __restrict__ W,
    const float* __restrict__ bias, const float* __restrict__ lng,
    const float* __restrict__ lnb, float* __restrict__ out) {
  constexpr int ROWS = 8;
  __shared__ float Xs[ROWS][Dm];
  __shared__ float Ys[ROWS][Dm];
  const int r0 = blockIdx.x * ROWS;
  const int tid = threadIdx.x;
  for (int i = tid; i < ROWS * Dm; i += 256)
    Xs[i / Dm][i % Dm] = X[(size_t)(r0 + i / Dm) * Dm + (i % Dm)];
  __syncthreads();
#pragma unroll
  for (int cc = 0; cc < 2; ++cc) {
    const int j = cc * 256 + tid;
    float acc[ROWS];
#pragma unroll
    for (int r = 0; r < ROWS; ++r) acc[r] = 0.f;
    const float* wrow = W + (size_t)j * Dm;
    for (int d = 0; d < Dm; d += 4) {
      const float4 w = ld4(wrow + d);
#pragma unroll
      for (int r = 0; r < ROWS; ++r) {
        acc[r] += Xs[r][d] * w.x + Xs[r][d + 1] * w.y + Xs[r][d + 2] * w.z + Xs[r][d + 3] * w.w;
      }
    }
    const float bb = bias[j];
#pragma unroll
    for (int r = 0; r < ROWS; ++r) Ys[r][j] = acc[r] + bb;
  }
  __syncthreads();
  const int wave = tid >> 6, lane = tid & 63;
  for (int r = wave; r < ROWS; r += 4) {
    float vals[8];
    float s = 0.f, sq = 0.f;
#pragma unroll
    for (int i = 0; i < 8; ++i) {
      const float v = Ys[r][lane + 64 * i];
      vals[i] = v; s += v; sq += v * v;
    }
#pragma unroll
    for (int m = 1; m < 64; m <<= 1) { s += __shfl_xor(s, m); sq += __shfl_xor(sq, m); }
    const float mu = s * (1.f / Dm);
    const float iv = rsqrtf(sq * (1.f / Dm) - mu * mu + LN_EPS);
#pragma unroll
    for (int i = 0; i < 8; ++i) {
      const int e = lane + 64 * i;
      out[(size_t)(r0 + r) * Dm + e] = (vals[i] - mu) * iv * lng[e] + lnb[e];
    }
  }
}

// ---------------------------------------------------------------------------
// u[bl,h,d] = scale * sum_c qh[bl, h*64+c] * Wk[h*64+c, d]
// ---------------------------------------------------------------------------
__global__ __launch_bounds__(256) void u_kernel(
    const float* __restrict__ qh, const float* __restrict__ Wk,
    float* __restrict__ u) {
  __shared__ float Xs[16][64];
  const int r0 = blockIdx.x * 16;
  const int h = blockIdx.y;
  const int tid = threadIdx.x;
  for (int i = tid; i < 16 * 64; i += 256)
    Xs[i >> 6][i & 63] = qh[(size_t)(r0 + (i >> 6)) * Dm + h * 64 + (i & 63)];
  __syncthreads();
#pragma unroll
  for (int cc = 0; cc < 2; ++cc) {
    const int j = cc * 256 + tid;
    float acc[16];
#pragma unroll
    for (int r = 0; r < 16; ++r) acc[r] = 0.f;
    for (int c = 0; c < 64; ++c) {
      const float wv = Wk[(size_t)(h * 64 + c) * Dm + j];
#pragma unroll
      for (int r = 0; r < 16; ++r) acc[r] += Xs[r][c] * wv;
    }
#pragma unroll
    for (int r = 0; r < 16; ++r)
      u[((size_t)(r0 + r) * Hn + h) * Dm + j] = acc[r] * 0.125f;  // DK^-0.5 folded
  }
}

// ---------------------------------------------------------------------------
// Fused per-(b,l) kernel: generate cond_k rows in registers, logits via u-dots,
// softmax over LK, weighted-sum s[bl,h,:]. One block per (b,l), 4 waves.
// ---------------------------------------------------------------------------
__global__ __launch_bounds__(256) void main_kernel(
    const float* __restrict__ gam, const float* __restrict__ bet,
    const float* __restrict__ cond_base, const float* __restrict__ kin,
    const float* __restrict__ ln2g, const float* __restrict__ ln2b,
    const float* __restrict__ u, float* __restrict__ sout) {
  __shared__ float w_s[Hn][LKn];          // logits -> softmax weights
  __shared__ float mu_s[LKn], iv_s[LKn];  // per-row LN stats, reused in pass B
  __shared__ float s_s[Hn][Dm];           // weighted sums
  const int bl = blockIdx.x;
  const int b = bl >> 5;  // LQ = 32
  const int tid = threadIdx.x, wave = tid >> 6, lane = tid & 63;
  const int d0 = lane * 4, d1 = 256 + lane * 4;

  for (int i = tid; i < Hn * Dm; i += 256) s_s[i >> 9][i & 511] = 0.f;

  // Per-lane parameters stay in registers: each lane only ever touches its 8 d's
  const float4 g0 = ld4(gam + (size_t)bl * Dm + d0), g1 = ld4(gam + (size_t)bl * Dm + d1);
  const float4 be0 = ld4(bet + (size_t)bl * Dm + d0), be1 = ld4(bet + (size_t)bl * Dm + d1);
  const float4 G0 = ld4(ln2g + d0), G1 = ld4(ln2g + d1);
  const float4 Bb0 = ld4(ln2b + d0), Bb1 = ld4(ln2b + d1);
  float4 u0[Hn], u1[Hn];
#pragma unroll
  for (int h = 0; h < Hn; ++h) {
    u0[h] = ld4(u + ((size_t)bl * Hn + h) * Dm + d0);
    u1[h] = ld4(u + ((size_t)bl * Hn + h) * Dm + d1);
  }
  __syncthreads();

  const float* cb = cond_base + (size_t)b * LKn * Dm;
  const float* kb = kin + (size_t)b * LKn * Dm;

  // ---- Pass A: logits ----
  for (int kk = wave * 64; kk < wave * 64 + 64; ++kk) {
    const float* crow = cb + (size_t)kk * Dm;
    const float* krow = kb + (size_t)kk * Dm;
    const float4 c0 = ld4(crow + d0), c1 = ld4(crow + d1);
    const float4 t0 = f4_fma(g0, c0, be0);
    const float4 t1 = f4_fma(g1, c1, be1);
    float ssum = f4_hsum(t0) + f4_hsum(t1);
    float ssq = f4_dot(t0, t0) + f4_dot(t1, t1);
#pragma unroll
    for (int m = 1; m < 64; m <<= 1) { ssum += __shfl_xor(ssum, m); ssq += __shfl_xor(ssq, m); }
    const float mu = ssum * (1.f / Dm);
    const float iv = rsqrtf(ssq * (1.f / Dm) - mu * mu + LN_EPS);
    if (lane == 0) { mu_s[kk] = mu; iv_s[kk] = iv; }
    const float4 k0 = ld4(krow + d0), k1 = ld4(krow + d1);
    const float4 y0 = f4_add(f4_fma(f4_muls(f4_subs(t0, mu), iv), G0, Bb0), k0);
    const float4 y1 = f4_add(f4_fma(f4_muls(f4_subs(t1, mu), iv), G1, Bb1), k1);
    float p[Hn];
#pragma unroll
    for (int h = 0; h < Hn; ++h) p[h] = f4_dot(y0, u0[h]) + f4_dot(y1, u1[h]);
#pragma unroll
    for (int m = 1; m < 64; m <<= 1) {
#pragma unroll
      for (int h = 0; h < Hn; ++h) p[h] += __shfl_xor(p[h], m);
    }
    if (lane < Hn) w_s[lane][kk] = p[lane];
  }
  __syncthreads();

  // ---- Softmax over LK per head (wave handles heads {wave, wave+4}) ----
  for (int h = wave; h < Hn; h += 4) {
    float v0 = w_s[h][lane], v1 = w_s[h][64 + lane], v2 = w_s[h][128 + lane], v3 = w_s[h][192 + lane];
    float mx = fmaxf(fmaxf(v0, v1), fmaxf(v2, v3));
#pragma unroll
    for (int m = 1; m < 64; m <<= 1) mx = fmaxf(mx, __shfl_xor(mx, m));
    const float e0 = __expf(v0 - mx), e1 = __expf(v1 - mx), e2 = __expf(v2 - mx), e3 = __expf(v3 - mx);
    float zs = (e0 + e1) + (e2 + e3);
#pragma unroll
    for (int m = 1; m < 64; m <<= 1) zs += __shfl_xor(zs, m);
    const float rz = 1.f / zs;
    w_s[h][lane] = e0 * rz; w_s[h][64 + lane] = e1 * rz;
    w_s[h][128 + lane] = e2 * rz; w_s[h][192 + lane] = e3 * rz;
  }
  __syncthreads();

  // ---- Pass B: weighted sums (rows regenerated with cached mu/iv) ----
  float4 a0[Hn], a1[Hn];
#pragma unroll
  for (int h = 0; h < Hn; ++h) {
    a0[h] = make_float4(0.f, 0.f, 0.f, 0.f);
    a1[h] = make_float4(0.f, 0.f, 0.f, 0.f);
  }
  for (int kk = wave * 64; kk < wave * 64 + 64; ++kk) {
    const float* crow = cb + (size_t)kk * Dm;
    const float* krow = kb + (size_t)kk * Dm;
    const float4 c0 = ld4(crow + d0), c1 = ld4(crow + d1);
    const float4 k0 = ld4(krow + d0), k1 = ld4(krow + d1);
    const float mu = mu_s[kk], iv = iv_s[kk];
    const float4 t0 = f4_fma(g0, c0, be0);
    const float4 t1 = f4_fma(g1, c1, be1);
    const float4 y0 = f4_add(f4_fma(f4_muls(f4_subs(t0, mu), iv), G0, Bb0), k0);
    const float4 y1 = f4_add(f4_fma(f4_muls(f4_subs(t1, mu), iv), G1, Bb1), k1);
#pragma unroll
    for (int h = 0; h < Hn; ++h) {
      const float wh = w_s[h][kk];
      a0[h].x = fmaf(wh, y0.x, a0[h].x); a0[h].y = fmaf(wh, y0.y, a0[h].y);
      a0[h].z = fmaf(wh, y0.z, a0[h].z); a0[h].w = fmaf(wh, y0.w, a0[h].w);
      a1[h].x = fmaf(wh, y1.x, a1[h].x); a1[h].y = fmaf(wh, y1.y, a1[h].y);
      a1[h].z = fmaf(wh, y1.z, a1[h].z); a1[h].w = fmaf(wh, y1.w, a1[h].w);
    }
  }
  // deterministic cross-wave accumulation (staggered, no atomics)
  for (int w = 0; w < 4; ++w) {
    if (wave == w) {
#pragma unroll
      for (int h = 0; h < Hn; ++h) {
        st4(&s_s[h][d0], f4_add(ld4(&s_s[h][d0]), a0[h]));
        st4(&s_s[h][d1], f4_add(ld4(&s_s[h][d1]), a1[h]));
      }
    }
    __syncthreads();
  }
  for (int i = tid; i < Hn * Dm; i += 256)
    sout[(size_t)bl * Hn * Dm + i] = s_s[i >> 9][i & 511];
}

// ---------------------------------------------------------------------------
// attn[bl, h*64+c] = sum_d s[bl,h,d] * Wv[h*64+c, d]
// ---------------------------------------------------------------------------
__global__ __launch_bounds__(256) void attnproj_kernel(
    const float* __restrict__ sbuf, const float* __restrict__ Wv,
    float* __restrict__ attn) {
  __shared__ float Xs[16][Dm];
  const int r0 = blockIdx.x * 16, h = blockIdx.y, tid = threadIdx.x;
  for (int i = tid; i < 16 * Dm; i += 256)
    Xs[i >> 9][i & 511] = sbuf[((size_t)(r0 + (i >> 9)) * Hn + h) * Dm + (i & 511)];
  __syncthreads();
  const int j = tid & 63, rg = tid >> 6;
  float acc[4] = {0.f, 0.f, 0.f, 0.f};
  const float* wrow = Wv + (size_t)(h * 64 + j) * Dm;
  for (int d = 0; d < Dm; d += 4) {
    const float4 w = ld4(wrow + d);
#pragma unroll
    for (int rr = 0; rr < 4; ++rr) {
      const int r = rg * 4 + rr;
      acc[rr] += Xs[r][d] * w.x + Xs[r][d + 1] * w.y + Xs[r][d + 2] * w.z + Xs[r][d + 3] * w.w;
    }
  }
#pragma unroll
  for (int rr = 0; rr < 4; ++rr)
    attn[(size_t)(r0 + rg * 4 + rr) * Dm + h * 64 + j] = acc[rr];
}

}  // namespace

extern "C" void kernel_launch(void* const* d_in, const int* in_sizes, int n_in,
                              void* d_out, int out_size, void* d_ws, size_t ws_size,
                              hipStream_t stream) {
  (void)in_sizes; (void)n_in; (void)out_size;
  const float* q    = (const float*)d_in[0];
  const float* k    = (const float*)d_in[1];
  // d_in[2] (v) is unused by the reference forward
  const float* Wq   = (const float*)d_in[3];
  const float* Wk   = (const float*)d_in[4];
  const float* Wv   = (const float*)d_in[5];
  const float* Wfc  = (const float*)d_in[6];
  const float* Wg   = (const float*)d_in[7];
  const float* bg   = (const float*)d_in[8];
  const float* Wvp  = (const float*)d_in[9];
  const float* bvp  = (const float*)d_in[10];
  const float* ln1g = (const float*)d_in[11];
  const float* ln1b = (const float*)d_in[12];
  const float* ln2g = (const float*)d_in[13];
  const float* ln2b = (const float*)d_in[14];
  float* out = (float*)d_out;

  // workspace layout (floats)
  float* ws = (float*)d_ws;
  const size_t NG = (size_t)NBL * Dm;        // 262144
  float* gammas    = ws;                     // [NBL, D]
  float* betas     = gammas + NG;            // [NBL, D]
  float* qh        = betas + NG;             // [NBL, D]
  float* attn      = qh + NG;                // [NBL, D]
  float* cond_base = attn + NG;              // [NBK, D]
  float* u         = cond_base + (size_t)NBK * Dm;  // [NBL, H, D]
  float* s         = u + (size_t)NBL * Hn * Dm;     // [NBL, H, D]
  const size_t need = ((size_t)(s + (size_t)NBL * Hn * Dm - ws)) * sizeof(float);
  if (ws_size < need) return;  // insufficient scratch -> fail loudly via validation

  const dim3 blk(256);
  // 1) FiLM params: gammas/betas = tanh(q @ Wg.T + bg)
  proj_kernel<8, 1><<<dim3(NBL / 8, 4), blk, 0, stream>>>(q, Wg, bg, gammas, betas, 2 * Dm, 256);
  // 2) cond_base = LN1(k @ Wvp.T + bvp)
  lnproj_kernel<<<dim3(NBK / 8), blk, 0, stream>>>(k, Wvp, bvp, ln1g, ln1b, cond_base);
  // 3) qh = q @ Wq.T
  proj_kernel<8, 0><<<dim3(NBL / 8, 2), blk, 0, stream>>>(q, Wq, nullptr, qh, nullptr, Dm, 256);
  // 4) u[bl,h,:] = scale * Wk_h^T qh_h   (logits vectors)
  u_kernel<<<dim3(NBL / 16, Hn), blk, 0, stream>>>(qh, Wk, u);
  // 5) fused: cond_k generation + logits + softmax + weighted sums
  main_kernel<<<dim3(NBL), blk, 0, stream>>>(gammas, betas, cond_base, k, ln2g, ln2b, u, s);
  // 6) attn[bl, h*64+c] = Wv_h @ s[bl,h,:]
  attnproj_kernel<<<dim3(NBL / 16, Hn), blk, 0, stream>>>(s, Wv, attn);
  // 7) out = attn @ Wfc.T
  proj_kernel<8, 0><<<dim3(NBL / 8, 2), blk, 0, stream>>>(attn, Wfc, nullptr, out, nullptr, Dm, 256);
}

// Round 3
// 129.933 us; speedup vs baseline: 2.8868x; 2.8868x over previous
//
#include <hip/hip_runtime.h>
#include <math.h>

namespace {
constexpr int Dm  = 512;
constexpr int Bn  = 16;
constexpr int LQn = 32;
constexpr int LKn = 256;
constexpr int Hn  = 8;
constexpr int NBL = Bn * LQn;  // 512
constexpr int NBK = Bn * LKn;  // 4096
constexpr float LN_EPS = 1e-5f;

typedef unsigned short u16;
typedef __attribute__((ext_vector_type(8))) short bh8;
typedef __attribute__((ext_vector_type(4))) float fv4;

__device__ __forceinline__ float4 ld4(const float* p) { return *reinterpret_cast<const float4*>(p); }
__device__ __forceinline__ void st4(float* p, float4 v) { *reinterpret_cast<float4*>(p) = v; }
__device__ __forceinline__ float4 f4_fma(float4 a, float4 b, float4 c) {
  return make_float4(fmaf(a.x, b.x, c.x), fmaf(a.y, b.y, c.y), fmaf(a.z, b.z, c.z), fmaf(a.w, b.w, c.w));
}
__device__ __forceinline__ float4 f4_add(float4 a, float4 b) {
  return make_float4(a.x + b.x, a.y + b.y, a.z + b.z, a.w + b.w);
}
__device__ __forceinline__ float4 f4_subs(float4 a, float s) {
  return make_float4(a.x - s, a.y - s, a.z - s, a.w - s);
}
__device__ __forceinline__ float4 f4_muls(float4 a, float s) {
  return make_float4(a.x * s, a.y * s, a.z * s, a.w * s);
}
__device__ __forceinline__ float f4_hsum(float4 a) { return (a.x + a.y) + (a.z + a.w); }
__device__ __forceinline__ float f4_dot(float4 a, float4 b) {
  return fmaf(a.x, b.x, fmaf(a.y, b.y, fmaf(a.z, b.z, a.w * b.w)));
}

__device__ __forceinline__ float b2f(u16 x) {
  union { float f; unsigned u; } c; c.u = ((unsigned)x) << 16; return c.f;
}
__device__ __forceinline__ u16 f2b(float f) {  // RTN-even
  union { float f; unsigned u; } c; c.f = f;
  unsigned u = c.u;
  u += 0x7FFFu + ((u >> 16) & 1u);
  return (u16)(u >> 16);
}
__device__ __forceinline__ unsigned pk2(float a, float b) {
  return (unsigned)f2b(a) | ((unsigned)f2b(b) << 16);
}
__device__ __forceinline__ uint4 pack8(const float* v) {
  uint4 r; r.x = pk2(v[0], v[1]); r.y = pk2(v[2], v[3]); r.z = pk2(v[4], v[5]); r.w = pk2(v[6], v[7]);
  return r;
}

// ===========================================================================
// Batched bf16 MFMA GEMM: C[z][r][c] = sum_k A[z][r][k] * B[z][c][k]  (A·B^T)
// 64x64 block tile, BK=32, 4 waves (2x2 of 32x32), 16x16x32 MFMA.
// ===========================================================================
struct GA {
  const u16* A; const u16* B;
  long lda, ldb, sAz, sBz;
  float* Cf; u16* Cb; float* Cf2;
  long ldc, sCz;
  int M, K;
  const float* e0; const float* e1; const float* e2; const float* e3;
  const float* e4; const float* e5; const float* e6;
};

// EPI: 0 = f32 store, 1 = bf16 store, 2 = film(tanh,split), 4 = +bias f32,
//      5 = u (row*8+z remap, *0.125), 6 = logits, 7 = s-epilogue
template <int EPI>
__global__ __launch_bounds__(256) void gemm_k(GA a) {
  __shared__ u16 As[64 * 32];
  __shared__ u16 Bs[64 * 32];
  const int z = blockIdx.z;
  const int bm0 = blockIdx.x * 64, bn0 = blockIdx.y * 64;
  const int t = threadIdx.x, lane = t & 63, w = t >> 6;
  const int wm = (w >> 1) * 32, wn = (w & 1) * 32;
  const u16* Ab = a.A + (long)z * a.sAz;
  const u16* Bb = a.B + (long)z * a.sBz;
  const int sr = t >> 2, sc = (t & 3) * 8;
  int arow = bm0 + sr; if (arow > a.M - 1) arow = a.M - 1;
  const u16* ap = Ab + (long)arow * a.lda + sc;
  const u16* bp = Bb + (long)(bn0 + sr) * a.ldb + sc;
  uint4* as_dst = (uint4*)&As[sr * 32 + sc];
  uint4* bs_dst = (uint4*)&Bs[sr * 32 + sc];

  fv4 zero = {0.f, 0.f, 0.f, 0.f};
  fv4 acc00 = zero, acc01 = zero, acc10 = zero, acc11 = zero;
  const int r0 = lane & 15, kq = (lane >> 4) * 8;
  const int nk = a.K >> 5;

  uint4 av = *(const uint4*)ap;
  uint4 bv = *(const uint4*)bp;
  for (int kt = 0; kt < nk; ++kt) {
    __syncthreads();
    *as_dst = av; *bs_dst = bv;
    __syncthreads();
    if (kt + 1 < nk) { ap += 32; bp += 32; av = *(const uint4*)ap; bv = *(const uint4*)bp; }
    bh8 a0 = *(const bh8*)&As[(wm + r0) * 32 + kq];
    bh8 a1 = *(const bh8*)&As[(wm + 16 + r0) * 32 + kq];
    bh8 b0 = *(const bh8*)&Bs[(wn + r0) * 32 + kq];
    bh8 b1 = *(const bh8*)&Bs[(wn + 16 + r0) * 32 + kq];
    acc00 = __builtin_amdgcn_mfma_f32_16x16x32_bf16(a0, b0, acc00, 0, 0, 0);
    acc01 = __builtin_amdgcn_mfma_f32_16x16x32_bf16(a0, b1, acc01, 0, 0, 0);
    acc10 = __builtin_amdgcn_mfma_f32_16x16x32_bf16(a1, b0, acc10, 0, 0, 0);
    acc11 = __builtin_amdgcn_mfma_f32_16x16x32_bf16(a1, b1, acc11, 0, 0, 0);
  }

  fv4 accs[2][2] = {{acc00, acc01}, {acc10, acc11}};
#pragma unroll
  for (int rb = 0; rb < 2; ++rb) {
#pragma unroll
    for (int cb2 = 0; cb2 < 2; ++cb2) {
#pragma unroll
      for (int j = 0; j < 4; ++j) {
        const int r = bm0 + wm + rb * 16 + (lane >> 4) * 4 + j;
        const int c = bn0 + wn + cb2 * 16 + (lane & 15);
        if (r >= a.M) continue;
        const float v = accs[rb][cb2][j];
        if (EPI == 0) {
          a.Cf[(long)z * a.sCz + (long)r * a.ldc + c] = v;
        } else if (EPI == 1) {
          a.Cb[(long)z * a.sCz + (long)r * a.ldc + c] = f2b(v);
        } else if (EPI == 2) {  // film
          const float x = tanhf(v + a.e0[c]);
          if (c < 512) a.Cf[(long)r * 512 + c] = x;
          else         a.Cf2[(long)r * 512 + (c - 512)] = x;
        } else if (EPI == 4) {  // + bias, f32
          a.Cf[(long)r * a.ldc + c] = v + a.e0[c];
        } else if (EPI == 5) {  // u: out row = r*8+z, scale 1/8
          a.Cb[((long)r * 8 + z) * a.ldc + c] = f2b(v * 0.125f);
        } else if (EPI == 6) {  // logits
          const int l = r >> 3;
          const int lh = z * 256 + r;
          const int bl = z * 32 + l;
          const float K1v = a.e0[(long)lh * 256 + c];
          const float* Pb = a.e1 + ((long)z * 96 + l) * 256 + c;
          const float P0 = Pb[0], P1 = Pb[32 * 256], P2 = Pb[64 * 256];
          const float mu = (P0 + a.e2[bl]) * (1.f / 512.f);
          const float msq = (P1 + 2.f * P2 + a.e3[bl]) * (1.f / 512.f);
          const float iv = rsqrtf(msq - mu * mu + LN_EPS);
          const float lg = K1v + a.e6[lh] + iv * (v + a.e4[lh] - mu * a.e5[lh]);
          a.Cf[(long)z * a.sCz + (long)r * a.ldc + c] = lg;
        } else if (EPI == 7) {  // s epilogue
          const int lh = z * 256 + r;
          const int bl = z * 32 + (r >> 3);
          const float T1v = a.e0[(long)lh * 512 + c];
          const float G2d = a.e1[c], B2d = a.e2[c];
          const float gv = a.e3[(long)bl * 512 + c];
          const float bev = a.e4[(long)bl * 512 + c];
          const float sv = T1v + B2d + G2d * (gv * v + bev * a.e5[lh] - a.e6[lh]);
          a.Cb[(long)z * a.sCz + (long)r * a.ldc + c] = f2b(sv);
        }
      }
    }
  }
}

// ===========================================================================
// prep_inputs: f32->bf16 copies + f32->bf16 transposes (WkT, kT)
// ===========================================================================
struct CopyArgs {
  const float* src[7];
  u16* dst[7];
  int cumb[8];
  const float* Wk; u16* WkT;
  const float* kf; u16* kT;
};

__device__ __forceinline__ void tp_core_f32(const float* src, long lds, u16* dst, long ldd,
                                            int tr, int tc, int t, float T[64][65]) {
  const int c = t & 63, rg = t >> 6;
#pragma unroll 4
  for (int i = 0; i < 16; ++i) {
    const int r = rg + 4 * i;
    T[r][c] = src[(long)(tr * 64 + r) * lds + tc * 64 + c];
  }
  __syncthreads();
#pragma unroll 4
  for (int i = 0; i < 16; ++i) {
    const int r = rg + 4 * i;
    dst[(long)(tc * 64 + r) * ldd + tr * 64 + c] = f2b(T[c][r]);
  }
}

__global__ __launch_bounds__(256) void prep_inputs_k(CopyArgs ca) {
  __shared__ float T[64][65];
  const int bid = blockIdx.x, t = threadIdx.x;
  if (bid < ca.cumb[7]) {
    int i = 0;
    while (bid >= ca.cumb[i + 1]) ++i;
    const long idx = (long)(bid - ca.cumb[i]) * 2048 + t * 8;
    const float* s = ca.src[i] + idx;
    const float4 x0 = ld4(s), x1 = ld4(s + 4);
    const float v[8] = {x0.x, x0.y, x0.z, x0.w, x1.x, x1.y, x1.z, x1.w};
    *(uint4*)(ca.dst[i] + idx) = pack8(v);
  } else if (bid < ca.cumb[7] + 64) {
    const int tt = bid - ca.cumb[7];
    tp_core_f32(ca.Wk, 512, ca.WkT, 512, tt >> 3, tt & 7, t, T);
  } else {
    const int tt = bid - ca.cumb[7] - 64;
    const int b = tt >> 5, w32 = tt & 31;
    tp_core_f32(ca.kf + (long)b * 131072, 512, ca.kT + (long)b * 131072, 256,
                w32 >> 3, w32 & 7, t, T);
  }
}

// bf16 -> bf16 transpose (cbT), per-b [256][512] -> [512][256], 512 blocks
__global__ __launch_bounds__(256) void tp_bf16_k(const u16* src, u16* dst) {
  __shared__ float T[64][65];
  const int tt = blockIdx.x, t = threadIdx.x;
  const int b = tt >> 5, w32 = tt & 31, tr = w32 >> 3, tc = w32 & 7;
  const u16* s = src + (long)b * 131072;
  u16* d = dst + (long)b * 131072;
  const int c = t & 63, rg = t >> 6;
#pragma unroll 4
  for (int i = 0; i < 16; ++i) {
    const int r = rg + 4 * i;
    T[r][c] = b2f(s[(long)(tr * 64 + r) * 512 + tc * 64 + c]);
  }
  __syncthreads();
#pragma unroll 4
  for (int i = 0; i < 16; ++i) {
    const int r = rg + 4 * i;
    d[(long)(tc * 64 + r) * 256 + tr * 64 + c] = f2b(T[c][r]);
  }
}

// ===========================================================================
// LN over rows of condpre -> cb_bf (and cb^2 -> cbsq_bf for the variance GEMM)
// 4 rows/block (wave per row).
// ===========================================================================
__global__ __launch_bounds__(256) void ln_k(const float* __restrict__ src,
                                            const float* __restrict__ g,
                                            const float* __restrict__ bb,
                                            u16* __restrict__ dst,
                                            u16* __restrict__ dstsq) {
  const int row = blockIdx.x * 4 + (threadIdx.x >> 6);
  const int lane = threadIdx.x & 63;
  const float* p = src + (long)row * 512 + lane * 8;
  const float4 x0 = ld4(p), x1 = ld4(p + 4);
  float v[8] = {x0.x, x0.y, x0.z, x0.w, x1.x, x1.y, x1.z, x1.w};
  float s = 0.f, sq = 0.f;
#pragma unroll
  for (int i = 0; i < 8; ++i) { s += v[i]; sq += v[i] * v[i]; }
#pragma unroll
  for (int m = 1; m < 64; m <<= 1) { s += __shfl_xor(s, m); sq += __shfl_xor(sq, m); }
  const float mu = s * (1.f / 512.f);
  const float iv = rsqrtf(sq * (1.f / 512.f) - mu * mu + LN_EPS);
  const float4 g0 = ld4(g + lane * 8), g1 = ld4(g + lane * 8 + 4);
  const float4 b0 = ld4(bb + lane * 8), b1 = ld4(bb + lane * 8 + 4);
  const float gg[8] = {g0.x, g0.y, g0.z, g0.w, g1.x, g1.y, g1.z, g1.w};
  const float bbv[8] = {b0.x, b0.y, b0.z, b0.w, b1.x, b1.y, b1.z, b1.w};
  float o[8], osq[8];
#pragma unroll
  for (int i = 0; i < 8; ++i) {
    o[i] = (v[i] - mu) * iv * gg[i] + bbv[i];
    osq[i] = o[i] * o[i];
  }
  *(uint4*)(dst + (long)row * 512 + lane * 8) = pack8(o);
  *(uint4*)(dstsq + (long)row * 512 + lane * 8) = pack8(osq);
}

// ===========================================================================
// prep: lh-rows (w1, c2/c3/c4) + bl-rows (A96, sum_be, sum_be2)
// ===========================================================================
__global__ __launch_bounds__(256) void prep_k(
    const u16* __restrict__ u_bf, const float* __restrict__ gam, const float* __restrict__ bet,
    const float* __restrict__ g2, const float* __restrict__ b2,
    u16* __restrict__ w1, float* __restrict__ c2, float* __restrict__ c3, float* __restrict__ c4,
    u16* __restrict__ A96, float* __restrict__ sum_be, float* __restrict__ sum_be2) {
  const int bid = blockIdx.x, t = threadIdx.x, lane = t & 63;
  const int e = lane * 8;
  if (bid < 1024) {
    const int lh = bid * 4 + (t >> 6);
    const int bl = lh >> 3;
    const uint4 up = *(const uint4*)(u_bf + (long)lh * 512 + e);
    const u16* us = (const u16*)&up;
    const float4 ga0 = ld4(gam + (long)bl * 512 + e), ga1 = ld4(gam + (long)bl * 512 + e + 4);
    const float4 be0 = ld4(bet + (long)bl * 512 + e), be1 = ld4(bet + (long)bl * 512 + e + 4);
    const float4 G0 = ld4(g2 + e), G1 = ld4(g2 + e + 4);
    const float4 B0 = ld4(b2 + e), B1 = ld4(b2 + e + 4);
    const float gv[8] = {ga0.x, ga0.y, ga0.z, ga0.w, ga1.x, ga1.y, ga1.z, ga1.w};
    const float bv[8] = {be0.x, be0.y, be0.z, be0.w, be1.x, be1.y, be1.z, be1.w};
    const float Gv[8] = {G0.x, G0.y, G0.z, G0.w, G1.x, G1.y, G1.z, G1.w};
    const float Bv[8] = {B0.x, B0.y, B0.z, B0.w, B1.x, B1.y, B1.z, B1.w};
    float wv[8]; float a2 = 0.f, a3 = 0.f, a4 = 0.f;
#pragma unroll
    for (int i = 0; i < 8; ++i) {
      const float uu = b2f(us[i]);
      const float t1 = Gv[i] * uu;
      wv[i] = gv[i] * t1;
      a2 += bv[i] * t1; a3 += t1; a4 += Bv[i] * uu;
    }
    *(uint4*)(w1 + (long)lh * 512 + e) = pack8(wv);
#pragma unroll
    for (int m = 1; m < 64; m <<= 1) {
      a2 += __shfl_xor(a2, m); a3 += __shfl_xor(a3, m); a4 += __shfl_xor(a4, m);
    }
    if (lane == 0) { c2[lh] = a2; c3[lh] = a3; c4[lh] = a4; }
  } else {
    const int bl = (bid - 1024) * 4 + (t >> 6);
    const int b = bl >> 5, l = bl & 31;
    const float4 ga0 = ld4(gam + (long)bl * 512 + e), ga1 = ld4(gam + (long)bl * 512 + e + 4);
    const float4 be0 = ld4(bet + (long)bl * 512 + e), be1 = ld4(bet + (long)bl * 512 + e + 4);
    const float gv[8] = {ga0.x, ga0.y, ga0.z, ga0.w, ga1.x, ga1.y, ga1.z, ga1.w};
    const float bv[8] = {be0.x, be0.y, be0.z, be0.w, be1.x, be1.y, be1.z, be1.w};
    float gg[8], gb[8]; float s1 = 0.f, s2 = 0.f;
#pragma unroll
    for (int i = 0; i < 8; ++i) {
      gg[i] = gv[i] * gv[i]; gb[i] = gv[i] * bv[i];
      s1 += bv[i]; s2 += bv[i] * bv[i];
    }
    const long base = ((long)b * 96 + l) * 512 + e;
    *(uint4*)(A96 + base) = pack8(gv);
    *(uint4*)(A96 + base + 32 * 512) = pack8(gg);
    *(uint4*)(A96 + base + 64 * 512) = pack8(gb);
#pragma unroll
    for (int m = 1; m < 64; m <<= 1) { s1 += __shfl_xor(s1, m); s2 += __shfl_xor(s2, m); }
    if (lane == 0) { sum_be[bl] = s1; sum_be2[bl] = s2; }
  }
}

// ===========================================================================
// softmax over logits rows -> w_bf, W1_bf (=w*iv), S1, S2
// ===========================================================================
__global__ __launch_bounds__(256) void softmax_k(
    const float* __restrict__ logits, const float* __restrict__ P,
    const float* __restrict__ sum_be, const float* __restrict__ sum_be2,
    u16* __restrict__ w_bf, u16* __restrict__ W1_bf,
    float* __restrict__ S1, float* __restrict__ S2) {
  const int lh = blockIdx.x * 4 + (threadIdx.x >> 6);
  const int lane = threadIdx.x & 63;
  const int b = lh >> 8, l = (lh >> 3) & 31, bl = lh >> 3;
  const int e = lane * 4;
  const float4 lg = ld4(logits + (long)lh * 256 + e);
  const float* Pb = P + ((long)b * 96 + l) * 256 + e;
  const float4 p0 = ld4(Pb), p1 = ld4(Pb + 32 * 256), p2 = ld4(Pb + 64 * 256);
  const float sbe = sum_be[bl], sbe2 = sum_be2[bl];
  const float lgs[4] = {lg.x, lg.y, lg.z, lg.w};
  const float p0s[4] = {p0.x, p0.y, p0.z, p0.w};
  const float p1s[4] = {p1.x, p1.y, p1.z, p1.w};
  const float p2s[4] = {p2.x, p2.y, p2.z, p2.w};
  float mu[4], iv[4];
#pragma unroll
  for (int i = 0; i < 4; ++i) {
    mu[i] = (p0s[i] + sbe) * (1.f / 512.f);
    const float msq = (p1s[i] + 2.f * p2s[i] + sbe2) * (1.f / 512.f);
    iv[i] = rsqrtf(msq - mu[i] * mu[i] + LN_EPS);
  }
  float mx = fmaxf(fmaxf(lgs[0], lgs[1]), fmaxf(lgs[2], lgs[3]));
#pragma unroll
  for (int m = 1; m < 64; m <<= 1) mx = fmaxf(mx, __shfl_xor(mx, m));
  float ex[4]; float z = 0.f;
#pragma unroll
  for (int i = 0; i < 4; ++i) { ex[i] = expf(lgs[i] - mx); z += ex[i]; }
#pragma unroll
  for (int m = 1; m < 64; m <<= 1) z += __shfl_xor(z, m);
  const float rz = 1.f / z;
  float wv[4], w1v[4]; float s1 = 0.f, s2 = 0.f;
#pragma unroll
  for (int i = 0; i < 4; ++i) {
    wv[i] = ex[i] * rz;
    w1v[i] = wv[i] * iv[i];
    s1 += w1v[i]; s2 += w1v[i] * mu[i];
  }
  uint2 wp, w1p;
  wp.x = pk2(wv[0], wv[1]); wp.y = pk2(wv[2], wv[3]);
  w1p.x = pk2(w1v[0], w1v[1]); w1p.y = pk2(w1v[2], w1v[3]);
  *(uint2*)(w_bf + (long)lh * 256 + e) = wp;
  *(uint2*)(W1_bf + (long)lh * 256 + e) = w1p;
#pragma unroll
  for (int m = 1; m < 64; m <<= 1) { s1 += __shfl_xor(s1, m); s2 += __shfl_xor(s2, m); }
  if (lane == 0) { S1[lh] = s1; S2[lh] = s2; }
}

// ===========================================================================
// ============== Fallback path (round-1 verified kernels) ===================
// ===========================================================================
template <int ROWS, int POST>
__global__ __launch_bounds__(256) void proj_kernel(
    const float* __restrict__ X, const float* __restrict__ W,
    const float* __restrict__ bias,
    float* __restrict__ out0, float* __restrict__ out1,
    int C_total, int cols_per_block) {
  __shared__ float Xs[ROWS][Dm];
  const int r0 = blockIdx.x * ROWS;
  const int tid = threadIdx.x;
  for (int i = tid; i < ROWS * Dm; i += 256)
    Xs[i / Dm][i % Dm] = X[(size_t)(r0 + i / Dm) * Dm + (i % Dm)];
  __syncthreads();
  const int j0 = blockIdx.y * cols_per_block;
  for (int j = j0 + tid; j < j0 + cols_per_block; j += 256) {
    float acc[ROWS];
#pragma unroll
    for (int r = 0; r < ROWS; ++r) acc[r] = 0.f;
    const float* wrow = W + (size_t)j * Dm;
    for (int d = 0; d < Dm; d += 4) {
      const float4 w = ld4(wrow + d);
#pragma unroll
      for (int r = 0; r < ROWS; ++r)
        acc[r] += Xs[r][d] * w.x + Xs[r][d + 1] * w.y + Xs[r][d + 2] * w.z + Xs[r][d + 3] * w.w;
    }
    const float bb = bias ? bias[j] : 0.f;
#pragma unroll
    for (int r = 0; r < ROWS; ++r) {
      float v = acc[r] + bb;
      if (POST == 1) {
        v = tanhf(v);
        const int Ch = C_total >> 1;
        if (j < Ch) out0[(size_t)(r0 + r) * Ch + j] = v;
        else        out1[(size_t)(r0 + r) * Ch + (j - Ch)] = v;
      } else {
        out0[(size_t)(r0 + r) * C_total + j] = v;
      }
    }
  }
}

__global__ __launch_bounds__(256) void lnproj_kernel(
    const float* __restrict__ X, const float* __restrict__ W,
    const float* __restrict__ bias, const float* __restrict__ lng,
    const float* __restrict__ lnb, float* __restrict__ out) {
  constexpr int ROWS = 8;
  __shared__ float Xs[ROWS][Dm];
  __shared__ float Ys[ROWS][Dm];
  const int r0 = blockIdx.x * ROWS;
  const int tid = threadIdx.x;
  for (int i = tid; i < ROWS * Dm; i += 256)
    Xs[i / Dm][i % Dm] = X[(size_t)(r0 + i / Dm) * Dm + (i % Dm)];
  __syncthreads();
#pragma unroll
  for (int cc = 0; cc < 2; ++cc) {
    const int j = cc * 256 + tid;
    float acc[ROWS];
#pragma unroll
    for (int r = 0; r < ROWS; ++r) acc[r] = 0.f;
    const float* wrow = W + (size_t)j * Dm;
    for (int d = 0; d < Dm; d += 4) {
      const float4 w = ld4(wrow + d);
#pragma unroll
      for (int r = 0; r < ROWS; ++r)
        acc[r] += Xs[r][d] * w.x + Xs[r][d + 1] * w.y + Xs[r][d + 2] * w.z + Xs[r][d + 3] * w.w;
    }
    const float bb = bias[j];
#pragma unroll
    for (int r = 0; r < ROWS; ++r) Ys[r][j] = acc[r] + bb;
  }
  __syncthreads();
  const int wave = tid >> 6, lane = tid & 63;
  for (int r = wave; r < ROWS; r += 4) {
    float vals[8];
    float s = 0.f, sq = 0.f;
#pragma unroll
    for (int i = 0; i < 8; ++i) {
      const float v = Ys[r][lane + 64 * i];
      vals[i] = v; s += v; sq += v * v;
    }
#pragma unroll
    for (int m = 1; m < 64; m <<= 1) { s += __shfl_xor(s, m); sq += __shfl_xor(sq, m); }
    const float mu = s * (1.f / Dm);
    const float iv = rsqrtf(sq * (1.f / Dm) - mu * mu + LN_EPS);
#pragma unroll
    for (int i = 0; i < 8; ++i) {
      const int e2 = lane + 64 * i;
      out[(size_t)(r0 + r) * Dm + e2] = (vals[i] - mu) * iv * lng[e2] + lnb[e2];
    }
  }
}

__global__ __launch_bounds__(256) void u_kernel(
    const float* __restrict__ qh, const float* __restrict__ Wk,
    float* __restrict__ u) {
  __shared__ float Xs[16][64];
  const int r0 = blockIdx.x * 16;
  const int h = blockIdx.y;
  const int tid = threadIdx.x;
  for (int i = tid; i < 16 * 64; i += 256)
    Xs[i >> 6][i & 63] = qh[(size_t)(r0 + (i >> 6)) * Dm + h * 64 + (i & 63)];
  __syncthreads();
#pragma unroll
  for (int cc = 0; cc < 2; ++cc) {
    const int j = cc * 256 + tid;
    float acc[16];
#pragma unroll
    for (int r = 0; r < 16; ++r) acc[r] = 0.f;
    for (int c = 0; c < 64; ++c) {
      const float wv = Wk[(size_t)(h * 64 + c) * Dm + j];
#pragma unroll
      for (int r = 0; r < 16; ++r) acc[r] += Xs[r][c] * wv;
    }
#pragma unroll
    for (int r = 0; r < 16; ++r)
      u[((size_t)(r0 + r) * Hn + h) * Dm + j] = acc[r] * 0.125f;
  }
}

__global__ __launch_bounds__(256) void main_kernel(
    const float* __restrict__ gam, const float* __restrict__ bet,
    const float* __restrict__ cond_base, const float* __restrict__ kin,
    const float* __restrict__ ln2g, const float* __restrict__ ln2b,
    const float* __restrict__ u, float* __restrict__ sout) {
  __shared__ float w_s[Hn][LKn];
  __shared__ float mu_s[LKn], iv_s[LKn];
  __shared__ float s_s[Hn][Dm];
  const int bl = blockIdx.x;
  const int b = bl >> 5;
  const int tid = threadIdx.x, wave = tid >> 6, lane = tid & 63;
  const int d0 = lane * 4, d1 = 256 + lane * 4;

  for (int i = tid; i < Hn * Dm; i += 256) s_s[i >> 9][i & 511] = 0.f;

  const float4 g0 = ld4(gam + (size_t)bl * Dm + d0), g1 = ld4(gam + (size_t)bl * Dm + d1);
  const float4 be0 = ld4(bet + (size_t)bl * Dm + d0), be1 = ld4(bet + (size_t)bl * Dm + d1);
  const float4 G0 = ld4(ln2g + d0), G1 = ld4(ln2g + d1);
  const float4 Bb0 = ld4(ln2b + d0), Bb1 = ld4(ln2b + d1);
  float4 u0[Hn], u1[Hn];
#pragma unroll
  for (int h = 0; h < Hn; ++h) {
    u0[h] = ld4(u + ((size_t)bl * Hn + h) * Dm + d0);
    u1[h] = ld4(u + ((size_t)bl * Hn + h) * Dm + d1);
  }
  __syncthreads();

  const float* cb = cond_base + (size_t)b * LKn * Dm;
  const float* kb = kin + (size_t)b * LKn * Dm;

  for (int kk = wave * 64; kk < wave * 64 + 64; ++kk) {
    const float* crow = cb + (size_t)kk * Dm;
    const float* krow = kb + (size_t)kk * Dm;
    const float4 c0 = ld4(crow + d0), c1 = ld4(crow + d1);
    const float4 t0 = f4_fma(g0, c0, be0);
    const float4 t1 = f4_fma(g1, c1, be1);
    float ssum = f4_hsum(t0) + f4_hsum(t1);
    float ssq = f4_dot(t0, t0) + f4_dot(t1, t1);
#pragma unroll
    for (int m = 1; m < 64; m <<= 1) { ssum += __shfl_xor(ssum, m); ssq += __shfl_xor(ssq, m); }
    const float mu = ssum * (1.f / Dm);
    const float iv = rsqrtf(ssq * (1.f / Dm) - mu * mu + LN_EPS);
    if (lane == 0) { mu_s[kk] = mu; iv_s[kk] = iv; }
    const float4 k0 = ld4(krow + d0), k1 = ld4(krow + d1);
    const float4 y0 = f4_add(f4_fma(f4_muls(f4_subs(t0, mu), iv), G0, Bb0), k0);
    const float4 y1 = f4_add(f4_fma(f4_muls(f4_subs(t1, mu), iv), G1, Bb1), k1);
    float p[Hn];
#pragma unroll
    for (int h = 0; h < Hn; ++h) p[h] = f4_dot(y0, u0[h]) + f4_dot(y1, u1[h]);
#pragma unroll
    for (int m = 1; m < 64; m <<= 1) {
#pragma unroll
      for (int h = 0; h < Hn; ++h) p[h] += __shfl_xor(p[h], m);
    }
    if (lane < Hn) w_s[lane][kk] = p[lane];
  }
  __syncthreads();

  for (int h = wave; h < Hn; h += 4) {
    float v0 = w_s[h][lane], v1 = w_s[h][64 + lane], v2 = w_s[h][128 + lane], v3 = w_s[h][192 + lane];
    float mx = fmaxf(fmaxf(v0, v1), fmaxf(v2, v3));
#pragma unroll
    for (int m = 1; m < 64; m <<= 1) mx = fmaxf(mx, __shfl_xor(mx, m));
    const float e0 = __expf(v0 - mx), e1 = __expf(v1 - mx), e2 = __expf(v2 - mx), e3 = __expf(v3 - mx);
    float zs = (e0 + e1) + (e2 + e3);
#pragma unroll
    for (int m = 1; m < 64; m <<= 1) zs += __shfl_xor(zs, m);
    const float rz = 1.f / zs;
    w_s[h][lane] = e0 * rz; w_s[h][64 + lane] = e1 * rz;
    w_s[h][128 + lane] = e2 * rz; w_s[h][192 + lane] = e3 * rz;
  }
  __syncthreads();

  float4 a0[Hn], a1[Hn];
#pragma unroll
  for (int h = 0; h < Hn; ++h) {
    a0[h] = make_float4(0.f, 0.f, 0.f, 0.f);
    a1[h] = make_float4(0.f, 0.f, 0.f, 0.f);
  }
  for (int kk = wave * 64; kk < wave * 64 + 64; ++kk) {
    const float* crow = cb + (size_t)kk * Dm;
    const float* krow = kb + (size_t)kk * Dm;
    const float4 c0 = ld4(crow + d0), c1 = ld4(crow + d1);
    const float4 k0 = ld4(krow + d0), k1 = ld4(krow + d1);
    const float mu = mu_s[kk], iv = iv_s[kk];
    const float4 t0 = f4_fma(g0, c0, be0);
    const float4 t1 = f4_fma(g1, c1, be1);
    const float4 y0 = f4_add(f4_fma(f4_muls(f4_subs(t0, mu), iv), G0, Bb0), k0);
    const float4 y1 = f4_add(f4_fma(f4_muls(f4_subs(t1, mu), iv), G1, Bb1), k1);
#pragma unroll
    for (int h = 0; h < Hn; ++h) {
      const float wh = w_s[h][kk];
      a0[h].x = fmaf(wh, y0.x, a0[h].x); a0[h].y = fmaf(wh, y0.y, a0[h].y);
      a0[h].z = fmaf(wh, y0.z, a0[h].z); a0[h].w = fmaf(wh, y0.w, a0[h].w);
      a1[h].x = fmaf(wh, y1.x, a1[h].x); a1[h].y = fmaf(wh, y1.y, a1[h].y);
      a1[h].z = fmaf(wh, y1.z, a1[h].z); a1[h].w = fmaf(wh, y1.w, a1[h].w);
    }
  }
  for (int w = 0; w < 4; ++w) {
    if (wave == w) {
#pragma unroll
      for (int h = 0; h < Hn; ++h) {
        st4(&s_s[h][d0], f4_add(ld4(&s_s[h][d0]), a0[h]));
        st4(&s_s[h][d1], f4_add(ld4(&s_s[h][d1]), a1[h]));
      }
    }
    __syncthreads();
  }
  for (int i = tid; i < Hn * Dm; i += 256)
    sout[(size_t)bl * Hn * Dm + i] = s_s[i >> 9][i & 511];
}

__global__ __launch_bounds__(256) void attnproj_kernel(
    const float* __restrict__ sbuf, const float* __restrict__ Wv,
    float* __restrict__ attn) {
  __shared__ float Xs[16][Dm];
  const int r0 = blockIdx.x * 16, h = blockIdx.y, tid = threadIdx.x;
  for (int i = tid; i < 16 * Dm; i += 256)
    Xs[i >> 9][i & 511] = sbuf[((size_t)(r0 + (i >> 9)) * Hn + h) * Dm + (i & 511)];
  __syncthreads();
  const int j = tid & 63, rg = tid >> 6;
  float acc[4] = {0.f, 0.f, 0.f, 0.f};
  const float* wrow = Wv + (size_t)(h * 64 + j) * Dm;
  for (int d = 0; d < Dm; d += 4) {
    const float4 w = ld4(wrow + d);
#pragma unroll
    for (int rr = 0; rr < 4; ++rr) {
      const int r = rg * 4 + rr;
      acc[rr] += Xs[r][d] * w.x + Xs[r][d + 1] * w.y + Xs[r][d + 2] * w.z + Xs[r][d + 3] * w.w;
    }
  }
#pragma unroll
  for (int rr = 0; rr < 4; ++rr)
    attn[(size_t)(r0 + rg * 4 + rr) * Dm + h * 64 + j] = acc[rr];
}

}  // namespace

extern "C" void kernel_launch(void* const* d_in, const int* in_sizes, int n_in,
                              void* d_out, int out_size, void* d_ws, size_t ws_size,
                              hipStream_t stream) {
  (void)in_sizes; (void)n_in; (void)out_size;
  const float* q    = (const float*)d_in[0];
  const float* k    = (const float*)d_in[1];
  const float* Wq   = (const float*)d_in[3];
  const float* Wk   = (const float*)d_in[4];
  const float* Wv   = (const float*)d_in[5];
  const float* Wfc  = (const float*)d_in[6];
  const float* Wg   = (const float*)d_in[7];
  const float* bg   = (const float*)d_in[8];
  const float* Wvp  = (const float*)d_in[9];
  const float* bvp  = (const float*)d_in[10];
  const float* ln1g = (const float*)d_in[11];
  const float* ln1b = (const float*)d_in[12];
  const float* ln2g = (const float*)d_in[13];
  const float* ln2b = (const float*)d_in[14];
  float* out = (float*)d_out;

  // ---- new-path workspace layout (bump allocator) ----
  char* base = (char*)d_ws;
  size_t off = 0;
  auto au16 = [&](size_t n) -> u16* {
    u16* p = (u16*)(base + off); off = (off + n * 2 + 255) & ~(size_t)255; return p;
  };
  auto af32 = [&](size_t n) -> float* {
    float* p = (float*)(base + off); off = (off + n * 4 + 255) & ~(size_t)255; return p;
  };
  u16* q_bf    = au16(262144);
  u16* Wg_bf   = au16(524288);
  u16* Wq_bf   = au16(262144);
  u16* Wvp_bf  = au16(262144);
  u16* WkT_bf  = au16(262144);
  u16* Wv_bf   = au16(262144);
  u16* Wfc_bf  = au16(262144);
  u16* k_bf    = au16(2097152);
  u16* kT_bf   = au16(2097152);
  u16* qh_bf   = au16(262144);
  float* gam   = af32(262144);
  float* bet   = af32(262144);
  float* condpre = af32(2097152);   // aliased as T1 later
  u16* cb_bf   = au16(2097152);
  u16* cbT_bf  = au16(2097152);
  u16* u_bf    = au16(2097152);
  u16* w1_bf   = au16(2097152);
  float* c2    = af32(4096);
  float* c3    = af32(4096);
  float* c4    = af32(4096);
  u16* A96_bf  = au16(16 * 96 * 512);
  float* sum_be  = af32(512);
  float* sum_be2 = af32(512);
  float* P     = af32(16 * 96 * 256);
  float* K1    = af32(1048576);     // aliased as s_bf later
  float* logits = af32(1048576);    // aliased as cbsq_bf before G5 writes it
  u16* w_bf    = au16(1048576);
  u16* W1_bf   = au16(1048576);
  float* S1    = af32(4096);
  float* S2    = af32(4096);
  u16* attn_bf = au16(262144);
  const size_t need_new = off;
  float* T1 = condpre;
  u16* s_bf = (u16*)K1;
  u16* cbsq_bf = (u16*)logits;  // cb^2 lives here from ln_k until G3b (G5 overwrites later)

  const dim3 blk(256);

  if (ws_size >= need_new) {
    // ---------------- new path: factorized bf16-MFMA pipeline ----------------
    // E1: convert + transposes
    CopyArgs ca;
    ca.src[0] = q;   ca.dst[0] = q_bf;
    ca.src[1] = Wg;  ca.dst[1] = Wg_bf;
    ca.src[2] = Wq;  ca.dst[2] = Wq_bf;
    ca.src[3] = Wvp; ca.dst[3] = Wvp_bf;
    ca.src[4] = Wv;  ca.dst[4] = Wv_bf;
    ca.src[5] = Wfc; ca.dst[5] = Wfc_bf;
    ca.src[6] = k;   ca.dst[6] = k_bf;
    const int nb[7] = {128, 256, 128, 128, 128, 128, 1024};
    int cum = 0;
    for (int i = 0; i < 7; ++i) { ca.cumb[i] = cum; cum += nb[i]; }
    ca.cumb[7] = cum;  // 1920
    ca.Wk = Wk; ca.WkT = WkT_bf; ca.kf = k; ca.kT = kT_bf;
    prep_inputs_k<<<dim3(cum + 64 + 512), blk, 0, stream>>>(ca);

    GA a = {};
    // G1a: film = tanh(q@Wg^T + bg) -> gam/bet
    a.A = q_bf; a.lda = 512; a.sAz = 0; a.B = Wg_bf; a.ldb = 512; a.sBz = 0;
    a.Cf = gam; a.Cf2 = bet; a.ldc = 512; a.sCz = 0; a.M = 512; a.K = 512; a.e0 = bg;
    gemm_k<2><<<dim3(8, 16, 1), blk, 0, stream>>>(a);
    // G1b: qh_bf = q@Wq^T
    a = {}; a.A = q_bf; a.lda = 512; a.B = Wq_bf; a.ldb = 512;
    a.Cb = qh_bf; a.ldc = 512; a.M = 512; a.K = 512;
    gemm_k<1><<<dim3(8, 8, 1), blk, 0, stream>>>(a);
    // G2: condpre = k@Wvp^T + bvp
    a = {}; a.A = k_bf; a.lda = 512; a.B = Wvp_bf; a.ldb = 512;
    a.Cf = condpre; a.ldc = 512; a.M = 4096; a.K = 512; a.e0 = bvp;
    gemm_k<4><<<dim3(64, 8, 1), blk, 0, stream>>>(a);
    // E2: LN1 -> cb_bf + cbsq_bf
    ln_k<<<dim3(1024), blk, 0, stream>>>(condpre, ln1g, ln1b, cb_bf, cbsq_bf);
    // E2b: cbT
    tp_bf16_k<<<dim3(512), blk, 0, stream>>>(cb_bf, cbT_bf);
    // Gu: u = 0.125 * qh_h @ Wk_h  (per-h)
    a = {}; a.A = qh_bf; a.lda = 512; a.sAz = 64; a.B = WkT_bf; a.ldb = 512; a.sBz = 64;
    a.Cb = u_bf; a.ldc = 512; a.sCz = 0; a.M = 512; a.K = 64;
    gemm_k<5><<<dim3(8, 8, 8), blk, 0, stream>>>(a);
    // E3: w1, c2/c3/c4, A96, sums
    prep_k<<<dim3(1152), blk, 0, stream>>>(u_bf, gam, bet, ln2g, ln2b,
                                           w1_bf, c2, c3, c4, A96_bf, sum_be, sum_be2);
    // G3: P = A96 @ cb^T (per-b) — rows 0..31 (g·cb) and 64..95 ((g·be)·cb) valid
    a = {}; a.A = A96_bf; a.lda = 512; a.sAz = 96 * 512;
    a.B = cb_bf; a.ldb = 512; a.sBz = 256 * 512;
    a.Cf = P; a.ldc = 256; a.sCz = 96 * 256; a.M = 96; a.K = 512;
    gemm_k<0><<<dim3(2, 4, 16), blk, 0, stream>>>(a);
    // G3b: middle block corrected — P[32..63] = g^2 @ (cb^2)^T
    a = {}; a.A = A96_bf + 32 * 512; a.lda = 512; a.sAz = 96 * 512;
    a.B = cbsq_bf; a.ldb = 512; a.sBz = 256 * 512;
    a.Cf = P + 32 * 256; a.ldc = 256; a.sCz = 96 * 256; a.M = 32; a.K = 512;
    gemm_k<0><<<dim3(1, 4, 16), blk, 0, stream>>>(a);
    // G4: K1 = u @ k^T (per-b)
    a = {}; a.A = u_bf; a.lda = 512; a.sAz = 256 * 512;
    a.B = k_bf; a.ldb = 512; a.sBz = 256 * 512;
    a.Cf = K1; a.ldc = 256; a.sCz = 256 * 256; a.M = 256; a.K = 512;
    gemm_k<0><<<dim3(4, 4, 16), blk, 0, stream>>>(a);
    // G5: K2 = w1 @ cb^T, fused logits epilogue (overwrites cbsq space)
    a = {}; a.A = w1_bf; a.lda = 512; a.sAz = 256 * 512;
    a.B = cb_bf; a.ldb = 512; a.sBz = 256 * 512;
    a.Cf = logits; a.ldc = 256; a.sCz = 256 * 256; a.M = 256; a.K = 512;
    a.e0 = K1; a.e1 = P; a.e2 = sum_be; a.e3 = sum_be2; a.e4 = c2; a.e5 = c3; a.e6 = c4;
    gemm_k<6><<<dim3(4, 4, 16), blk, 0, stream>>>(a);
    // E4: softmax -> w_bf, W1_bf, S1, S2
    softmax_k<<<dim3(1024), blk, 0, stream>>>(logits, P, sum_be, sum_be2,
                                              w_bf, W1_bf, S1, S2);
    // G6: T1 = w @ (kT)^T (per-b)
    a = {}; a.A = w_bf; a.lda = 256; a.sAz = 256 * 256;
    a.B = kT_bf; a.ldb = 256; a.sBz = 512 * 256;
    a.Cf = T1; a.ldc = 512; a.sCz = 256 * 512; a.M = 256; a.K = 256;
    gemm_k<0><<<dim3(4, 8, 16), blk, 0, stream>>>(a);
    // G7: T2 = W1 @ (cbT)^T, fused s epilogue -> s_bf
    a = {}; a.A = W1_bf; a.lda = 256; a.sAz = 256 * 256;
    a.B = cbT_bf; a.ldb = 256; a.sBz = 512 * 256;
    a.Cb = s_bf; a.ldc = 512; a.sCz = 256 * 512; a.M = 256; a.K = 256;
    a.e0 = T1; a.e1 = ln2g; a.e2 = ln2b; a.e3 = gam; a.e4 = bet; a.e5 = S1; a.e6 = S2;
    gemm_k<7><<<dim3(4, 8, 16), blk, 0, stream>>>(a);
    // G8: attn = s_h @ Wv_h^T (per-h)
    a = {}; a.A = s_bf; a.lda = 4096; a.sAz = 512;
    a.B = Wv_bf; a.ldb = 512; a.sBz = 64 * 512;
    a.Cb = attn_bf; a.ldc = 512; a.sCz = 64; a.M = 512; a.K = 512;
    gemm_k<1><<<dim3(8, 1, 8), blk, 0, stream>>>(a);
    // G9: out = attn @ Wfc^T (f32)
    a = {}; a.A = attn_bf; a.lda = 512; a.B = Wfc_bf; a.ldb = 512;
    a.Cf = out; a.ldc = 512; a.M = 512; a.K = 512;
    gemm_k<0><<<dim3(8, 8, 1), blk, 0, stream>>>(a);
  } else {
    // ---------------- fallback: round-1 verified path ----------------
    float* ws = (float*)d_ws;
    const size_t NG = (size_t)NBL * Dm;
    float* gammas    = ws;
    float* betas     = gammas + NG;
    float* qh        = betas + NG;
    float* attn      = qh + NG;
    float* cond_base = attn + NG;
    float* u         = cond_base + (size_t)NBK * Dm;
    float* s         = u + (size_t)NBL * Hn * Dm;
    const size_t need_old = ((size_t)(s + (size_t)NBL * Hn * Dm - ws)) * sizeof(float);
    if (ws_size < need_old) return;

    proj_kernel<8, 1><<<dim3(NBL / 8, 4), blk, 0, stream>>>(q, Wg, bg, gammas, betas, 2 * Dm, 256);
    lnproj_kernel<<<dim3(NBK / 8), blk, 0, stream>>>(k, Wvp, bvp, ln1g, ln1b, cond_base);
    proj_kernel<8, 0><<<dim3(NBL / 8, 2), blk, 0, stream>>>(q, Wq, nullptr, qh, nullptr, Dm, 256);
    u_kernel<<<dim3(NBL / 16, Hn), blk, 0, stream>>>(qh, Wk, u);
    main_kernel<<<dim3(NBL), blk, 0, stream>>>(gammas, betas, cond_base, k, ln2g, ln2b, u, s);
    attnproj_kernel<<<dim3(NBL / 16, Hn), blk, 0, stream>>>(s, Wv, attn);
    proj_kernel<8, 0><<<dim3(NBL / 8, 2), blk, 0, stream>>>(attn, Wfc, nullptr, out, nullptr, Dm, 256);
  }
}

// Round 4
// 106.515 us; speedup vs baseline: 3.5215x; 1.2199x over previous
//
#include <hip/hip_runtime.h>
#include <math.h>

namespace {
constexpr int Dm  = 512;
constexpr int Bn  = 16;
constexpr int LQn = 32;
constexpr int LKn = 256;
constexpr int Hn  = 8;
constexpr int NBL = Bn * LQn;  // 512
constexpr int NBK = Bn * LKn;  // 4096
constexpr float LN_EPS = 1e-5f;

typedef unsigned short u16;
typedef __attribute__((ext_vector_type(8))) short bh8;
typedef __attribute__((ext_vector_type(4))) float fv4;

__device__ __forceinline__ float4 ld4(const float* p) { return *reinterpret_cast<const float4*>(p); }
__device__ __forceinline__ void st4(float* p, float4 v) { *reinterpret_cast<float4*>(p) = v; }
__device__ __forceinline__ float4 f4_fma(float4 a, float4 b, float4 c) {
  return make_float4(fmaf(a.x, b.x, c.x), fmaf(a.y, b.y, c.y), fmaf(a.z, b.z, c.z), fmaf(a.w, b.w, c.w));
}
__device__ __forceinline__ float4 f4_add(float4 a, float4 b) {
  return make_float4(a.x + b.x, a.y + b.y, a.z + b.z, a.w + b.w);
}
__device__ __forceinline__ float4 f4_subs(float4 a, float s) {
  return make_float4(a.x - s, a.y - s, a.z - s, a.w - s);
}
__device__ __forceinline__ float4 f4_muls(float4 a, float s) {
  return make_float4(a.x * s, a.y * s, a.z * s, a.w * s);
}
__device__ __forceinline__ float f4_hsum(float4 a) { return (a.x + a.y) + (a.z + a.w); }
__device__ __forceinline__ float f4_dot(float4 a, float4 b) {
  return fmaf(a.x, b.x, fmaf(a.y, b.y, fmaf(a.z, b.z, a.w * b.w)));
}

__device__ __forceinline__ float b2f(u16 x) {
  union { float f; unsigned u; } c; c.u = ((unsigned)x) << 16; return c.f;
}
__device__ __forceinline__ u16 f2b(float f) {  // RTN-even
  union { float f; unsigned u; } c; c.f = f;
  unsigned u = c.u;
  u += 0x7FFFu + ((u >> 16) & 1u);
  return (u16)(u >> 16);
}
__device__ __forceinline__ unsigned pk2(float a, float b) {
  return (unsigned)f2b(a) | ((unsigned)f2b(b) << 16);
}
__device__ __forceinline__ uint4 pack8(const float* v) {
  uint4 r; r.x = pk2(v[0], v[1]); r.y = pk2(v[2], v[3]); r.z = pk2(v[4], v[5]); r.w = pk2(v[6], v[7]);
  return r;
}

// XOR-swizzled LDS tile access: [64][64] u16, 16B slots, c8 ^= row&7
// -> stride-128B rows spread across 8 bank slots (T2/G4 swizzle).
__device__ __forceinline__ bh8 lds_rd(const u16* S, int row, int c8) {
  return *(const bh8*)&S[row * 64 + ((c8 ^ (row & 7)) << 3)];
}

// ===========================================================================
// Batched bf16 MFMA GEMM: C[z][r][c] = sum_k A[z][r][k] * B[z][c][k]  (A·B^T)
// 64x64 tile, BK=64, 4 waves (2x2 of 32x32), swizzled LDS, reg prefetch.
// Balt: if set, blocks with bm0>=64 read B from Balt (GP's cb^2 rows).
// ===========================================================================
struct GA {
  const u16* A; const u16* B; const u16* Balt;
  long lda, ldb, sAz, sBz;
  float* Cf; u16* Cb; float* Cf2;
  long ldc, sCz;
  int M, K;
  const float* e0;
};

// EPI: 0 = f32 store, 1 = bf16 store, 2 = film(tanh,split), 4 = +bias f32,
//      5 = u (row*8+z remap, *0.125)
template <int EPI>
__global__ __launch_bounds__(256) void gemm_k(GA a) {
  __shared__ u16 As[64 * 64];
  __shared__ u16 Bs[64 * 64];
  const int z = blockIdx.z;
  const int bm0 = blockIdx.x * 64, bn0 = blockIdx.y * 64;
  const int t = threadIdx.x, lane = t & 63, w = t >> 6;
  const int wm = (w >> 1) * 32, wn = (w & 1) * 32;
  const u16* Ab = a.A + (long)z * a.sAz;
  const u16* Bbase = (a.Balt != nullptr && bm0 >= 64) ? a.Balt : a.B;
  const u16* Bb = Bbase + (long)z * a.sBz;

  // staging: thread t loads 16B at (row = t>>3 [+32], col = (t&7)*8), 2 rounds
  const int sr = t >> 3, sc8 = t & 7, sc = sc8 * 8;
  int ar0 = bm0 + sr;      if (ar0 > a.M - 1) ar0 = a.M - 1;
  int ar1 = bm0 + sr + 32; if (ar1 > a.M - 1) ar1 = a.M - 1;
  const u16* ap0 = Ab + (long)ar0 * a.lda + sc;
  const u16* ap1 = Ab + (long)ar1 * a.lda + sc;
  const u16* bp0 = Bb + (long)(bn0 + sr) * a.ldb + sc;
  const u16* bp1 = Bb + (long)(bn0 + sr + 32) * a.ldb + sc;
  const int iA0 = sr * 64 + ((sc8 ^ (sr & 7)) << 3);
  const int iA1 = iA0 + 32 * 64;

  fv4 zero = {0.f, 0.f, 0.f, 0.f};
  fv4 acc00 = zero, acc01 = zero, acc10 = zero, acc11 = zero;
  const int r0 = lane & 15, kq8 = lane >> 4;  // col8 base 0..3
  const int nk = a.K >> 6;

  uint4 av0 = *(const uint4*)ap0, av1 = *(const uint4*)ap1;
  uint4 bv0 = *(const uint4*)bp0, bv1 = *(const uint4*)bp1;
  for (int kt = 0; kt < nk; ++kt) {
    __syncthreads();
    *(uint4*)&As[iA0] = av0; *(uint4*)&As[iA1] = av1;
    *(uint4*)&Bs[iA0] = bv0; *(uint4*)&Bs[iA1] = bv1;
    __syncthreads();
    if (kt + 1 < nk) {
      ap0 += 64; ap1 += 64; bp0 += 64; bp1 += 64;
      av0 = *(const uint4*)ap0; av1 = *(const uint4*)ap1;
      bv0 = *(const uint4*)bp0; bv1 = *(const uint4*)bp1;
    }
#pragma unroll
    for (int kc = 0; kc < 2; ++kc) {
      const int c8 = kq8 + 4 * kc;
      bh8 aa0 = lds_rd(As, wm + r0, c8);
      bh8 aa1 = lds_rd(As, wm + 16 + r0, c8);
      bh8 bb0 = lds_rd(Bs, wn + r0, c8);
      bh8 bb1 = lds_rd(Bs, wn + 16 + r0, c8);
      acc00 = __builtin_amdgcn_mfma_f32_16x16x32_bf16(aa0, bb0, acc00, 0, 0, 0);
      acc01 = __builtin_amdgcn_mfma_f32_16x16x32_bf16(aa0, bb1, acc01, 0, 0, 0);
      acc10 = __builtin_amdgcn_mfma_f32_16x16x32_bf16(aa1, bb0, acc10, 0, 0, 0);
      acc11 = __builtin_amdgcn_mfma_f32_16x16x32_bf16(aa1, bb1, acc11, 0, 0, 0);
    }
  }

  fv4 accs[2][2] = {{acc00, acc01}, {acc10, acc11}};
#pragma unroll
  for (int rb = 0; rb < 2; ++rb) {
#pragma unroll
    for (int cbl = 0; cbl < 2; ++cbl) {
#pragma unroll
      for (int j = 0; j < 4; ++j) {
        const int r = bm0 + wm + rb * 16 + (lane >> 4) * 4 + j;
        const int c = bn0 + wn + cbl * 16 + (lane & 15);
        if (r >= a.M) continue;
        const float v = accs[rb][cbl][j];
        if (EPI == 0) {
          a.Cf[(long)z * a.sCz + (long)r * a.ldc + c] = v;
        } else if (EPI == 1) {
          a.Cb[(long)z * a.sCz + (long)r * a.ldc + c] = f2b(v);
        } else if (EPI == 2) {  // film
          const float x = tanhf(v + a.e0[c]);
          if (c < 512) a.Cf[(long)r * 512 + c] = x;
          else         a.Cf2[(long)r * 512 + (c - 512)] = x;
        } else if (EPI == 4) {  // + bias, f32
          a.Cf[(long)r * a.ldc + c] = v + a.e0[c];
        } else if (EPI == 5) {  // u: out row = r*8+z, scale 1/8
          a.Cb[((long)r * 8 + z) * a.ldc + c] = f2b(v * 0.125f);
        }
      }
    }
  }
}

// ===========================================================================
// Dual batched GEMM: two A·B^T with identical (z, r, c) output coordinates.
// v1 = A1·B1^T, v2 = A2·B2^T, fused epilogue. 16 MFMA per barrier-pair.
// EPI: 0 = logits (K1,K2), 1 = s (T1,T2)
// ===========================================================================
struct GA2 {
  const u16* A1; const u16* A2; const u16* B1; const u16* B2;
  long lda, ldb, sAz, sBz;
  float* Cf; u16* Cb;
  long ldc, sCz;
  int M, K;
  const float* e1; const float* e2; const float* e3;
  const float* e4; const float* e5; const float* e6;
};

template <int EPI>
__global__ __launch_bounds__(256) void gemm2_k(GA2 a) {
  __shared__ u16 As1[64 * 64];
  __shared__ u16 As2[64 * 64];
  __shared__ u16 Bs1[64 * 64];
  __shared__ u16 Bs2[64 * 64];
  const int z = blockIdx.z;
  const int bm0 = blockIdx.x * 64, bn0 = blockIdx.y * 64;
  const int t = threadIdx.x, lane = t & 63, w = t >> 6;
  const int wm = (w >> 1) * 32, wn = (w & 1) * 32;
  const u16* A1b = a.A1 + (long)z * a.sAz;
  const u16* A2b = a.A2 + (long)z * a.sAz;
  const u16* B1b = a.B1 + (long)z * a.sBz;
  const u16* B2b = a.B2 + (long)z * a.sBz;

  const int sr = t >> 3, sc8 = t & 7, sc = sc8 * 8;
  const long aoff0 = (long)(bm0 + sr) * a.lda + sc;
  const long aoff1 = (long)(bm0 + sr + 32) * a.lda + sc;
  const long boff0 = (long)(bn0 + sr) * a.ldb + sc;
  const long boff1 = (long)(bn0 + sr + 32) * a.ldb + sc;
  const u16 *a1p0 = A1b + aoff0, *a1p1 = A1b + aoff1;
  const u16 *a2p0 = A2b + aoff0, *a2p1 = A2b + aoff1;
  const u16 *b1p0 = B1b + boff0, *b1p1 = B1b + boff1;
  const u16 *b2p0 = B2b + boff0, *b2p1 = B2b + boff1;
  const int iA0 = sr * 64 + ((sc8 ^ (sr & 7)) << 3);
  const int iA1 = iA0 + 32 * 64;

  fv4 zero = {0.f, 0.f, 0.f, 0.f};
  fv4 p00 = zero, p01 = zero, p10 = zero, p11 = zero;  // pair 1
  fv4 q00 = zero, q01 = zero, q10 = zero, q11 = zero;  // pair 2
  const int r0 = lane & 15, kq8 = lane >> 4;
  const int nk = a.K >> 6;

  uint4 a1v0 = *(const uint4*)a1p0, a1v1 = *(const uint4*)a1p1;
  uint4 a2v0 = *(const uint4*)a2p0, a2v1 = *(const uint4*)a2p1;
  uint4 b1v0 = *(const uint4*)b1p0, b1v1 = *(const uint4*)b1p1;
  uint4 b2v0 = *(const uint4*)b2p0, b2v1 = *(const uint4*)b2p1;
  for (int kt = 0; kt < nk; ++kt) {
    __syncthreads();
    *(uint4*)&As1[iA0] = a1v0; *(uint4*)&As1[iA1] = a1v1;
    *(uint4*)&As2[iA0] = a2v0; *(uint4*)&As2[iA1] = a2v1;
    *(uint4*)&Bs1[iA0] = b1v0; *(uint4*)&Bs1[iA1] = b1v1;
    *(uint4*)&Bs2[iA0] = b2v0; *(uint4*)&Bs2[iA1] = b2v1;
    __syncthreads();
    if (kt + 1 < nk) {
      a1p0 += 64; a1p1 += 64; a2p0 += 64; a2p1 += 64;
      b1p0 += 64; b1p1 += 64; b2p0 += 64; b2p1 += 64;
      a1v0 = *(const uint4*)a1p0; a1v1 = *(const uint4*)a1p1;
      a2v0 = *(const uint4*)a2p0; a2v1 = *(const uint4*)a2p1;
      b1v0 = *(const uint4*)b1p0; b1v1 = *(const uint4*)b1p1;
      b2v0 = *(const uint4*)b2p0; b2v1 = *(const uint4*)b2p1;
    }
#pragma unroll
    for (int kc = 0; kc < 2; ++kc) {
      const int c8 = kq8 + 4 * kc;
      bh8 x0 = lds_rd(As1, wm + r0, c8);
      bh8 x1 = lds_rd(As1, wm + 16 + r0, c8);
      bh8 y0 = lds_rd(Bs1, wn + r0, c8);
      bh8 y1 = lds_rd(Bs1, wn + 16 + r0, c8);
      p00 = __builtin_amdgcn_mfma_f32_16x16x32_bf16(x0, y0, p00, 0, 0, 0);
      p01 = __builtin_amdgcn_mfma_f32_16x16x32_bf16(x0, y1, p01, 0, 0, 0);
      p10 = __builtin_amdgcn_mfma_f32_16x16x32_bf16(x1, y0, p10, 0, 0, 0);
      p11 = __builtin_amdgcn_mfma_f32_16x16x32_bf16(x1, y1, p11, 0, 0, 0);
      bh8 u0 = lds_rd(As2, wm + r0, c8);
      bh8 u1 = lds_rd(As2, wm + 16 + r0, c8);
      bh8 v0 = lds_rd(Bs2, wn + r0, c8);
      bh8 v1 = lds_rd(Bs2, wn + 16 + r0, c8);
      q00 = __builtin_amdgcn_mfma_f32_16x16x32_bf16(u0, v0, q00, 0, 0, 0);
      q01 = __builtin_amdgcn_mfma_f32_16x16x32_bf16(u0, v1, q01, 0, 0, 0);
      q10 = __builtin_amdgcn_mfma_f32_16x16x32_bf16(u1, v0, q10, 0, 0, 0);
      q11 = __builtin_amdgcn_mfma_f32_16x16x32_bf16(u1, v1, q11, 0, 0, 0);
    }
  }

  fv4 pa[2][2] = {{p00, p01}, {p10, p11}};
  fv4 qa[2][2] = {{q00, q01}, {q10, q11}};
#pragma unroll
  for (int rb = 0; rb < 2; ++rb) {
#pragma unroll
    for (int cbl = 0; cbl < 2; ++cbl) {
#pragma unroll
      for (int j = 0; j < 4; ++j) {
        const int r = bm0 + wm + rb * 16 + (lane >> 4) * 4 + j;
        const int c = bn0 + wn + cbl * 16 + (lane & 15);
        if (r >= a.M) continue;
        const float v1 = pa[rb][cbl][j];
        const float v2 = qa[rb][cbl][j];
        if (EPI == 0) {  // logits: v1=K1, v2=K2
          const int l = r >> 3;
          const int lh = z * 256 + r;
          const int bl = z * 32 + l;
          const float* Pb = a.e1 + ((long)z * 96 + l) * 256 + c;
          const float P0 = Pb[0], Pgb = Pb[32 * 256], Pg2 = Pb[64 * 256];
          const float mu = (P0 + a.e2[bl]) * (1.f / 512.f);
          const float msq = (Pg2 + 2.f * Pgb + a.e3[bl]) * (1.f / 512.f);
          const float iv = rsqrtf(msq - mu * mu + LN_EPS);
          const float lg = v1 + a.e6[lh] + iv * (v2 + a.e4[lh] - mu * a.e5[lh]);
          a.Cf[(long)z * a.sCz + (long)r * a.ldc + c] = lg;
        } else {  // s: v1=T1, v2=T2
          const int lh = z * 256 + r;
          const int bl = z * 32 + (r >> 3);
          const float G2d = a.e1[c], B2d = a.e2[c];
          const float gv = a.e3[(long)bl * 512 + c];
          const float bev = a.e4[(long)bl * 512 + c];
          const float sv = v1 + B2d + G2d * (gv * v2 + bev * a.e5[lh] - a.e6[lh]);
          a.Cb[(long)z * a.sCz + (long)r * a.ldc + c] = f2b(sv);
        }
      }
    }
  }
}

// ===========================================================================
// prep_inputs: f32->bf16 copies + f32->bf16 transposes (WkT, kT)
// ===========================================================================
struct CopyArgs {
  const float* src[7];
  u16* dst[7];
  int cumb[8];
  const float* Wk; u16* WkT;
  const float* kf; u16* kT;
};

__device__ __forceinline__ void tp_core_f32(const float* src, long lds, u16* dst, long ldd,
                                            int tr, int tc, int t, float T[64][65]) {
  const int c = t & 63, rg = t >> 6;
#pragma unroll 4
  for (int i = 0; i < 16; ++i) {
    const int r = rg + 4 * i;
    T[r][c] = src[(long)(tr * 64 + r) * lds + tc * 64 + c];
  }
  __syncthreads();
#pragma unroll 4
  for (int i = 0; i < 16; ++i) {
    const int r = rg + 4 * i;
    dst[(long)(tc * 64 + r) * ldd + tr * 64 + c] = f2b(T[c][r]);
  }
}

__global__ __launch_bounds__(256) void prep_inputs_k(CopyArgs ca) {
  __shared__ float T[64][65];
  const int bid = blockIdx.x, t = threadIdx.x;
  if (bid < ca.cumb[7]) {
    int i = 0;
    while (bid >= ca.cumb[i + 1]) ++i;
    const long idx = (long)(bid - ca.cumb[i]) * 2048 + t * 8;
    const float* s = ca.src[i] + idx;
    const float4 x0 = ld4(s), x1 = ld4(s + 4);
    const float v[8] = {x0.x, x0.y, x0.z, x0.w, x1.x, x1.y, x1.z, x1.w};
    *(uint4*)(ca.dst[i] + idx) = pack8(v);
  } else if (bid < ca.cumb[7] + 64) {
    const int tt = bid - ca.cumb[7];
    tp_core_f32(ca.Wk, 512, ca.WkT, 512, tt >> 3, tt & 7, t, T);
  } else {
    const int tt = bid - ca.cumb[7] - 64;
    const int b = tt >> 5, w32 = tt & 31;
    tp_core_f32(ca.kf + (long)b * 131072, 512, ca.kT + (long)b * 131072, 256,
                w32 >> 3, w32 & 7, t, T);
  }
}

// bf16 -> bf16 transpose (cbT), per-b [256][512] -> [512][256], 512 blocks
__global__ __launch_bounds__(256) void tp_bf16_k(const u16* src, u16* dst) {
  __shared__ float T[64][65];
  const int tt = blockIdx.x, t = threadIdx.x;
  const int b = tt >> 5, w32 = tt & 31, tr = w32 >> 3, tc = w32 & 7;
  const u16* s = src + (long)b * 131072;
  u16* d = dst + (long)b * 131072;
  const int c = t & 63, rg = t >> 6;
#pragma unroll 4
  for (int i = 0; i < 16; ++i) {
    const int r = rg + 4 * i;
    T[r][c] = b2f(s[(long)(tr * 64 + r) * 512 + tc * 64 + c]);
  }
  __syncthreads();
#pragma unroll 4
  for (int i = 0; i < 16; ++i) {
    const int r = rg + 4 * i;
    d[(long)(tc * 64 + r) * 256 + tr * 64 + c] = f2b(T[c][r]);
  }
}

// ===========================================================================
// LN over rows of condpre -> cb_bf (and cb^2 -> cbsq_bf for the variance GEMM)
// ===========================================================================
__global__ __launch_bounds__(256) void ln_k(const float* __restrict__ src,
                                            const float* __restrict__ g,
                                            const float* __restrict__ bb,
                                            u16* __restrict__ dst,
                                            u16* __restrict__ dstsq) {
  const int row = blockIdx.x * 4 + (threadIdx.x >> 6);
  const int lane = threadIdx.x & 63;
  const float* p = src + (long)row * 512 + lane * 8;
  const float4 x0 = ld4(p), x1 = ld4(p + 4);
  float v[8] = {x0.x, x0.y, x0.z, x0.w, x1.x, x1.y, x1.z, x1.w};
  float s = 0.f, sq = 0.f;
#pragma unroll
  for (int i = 0; i < 8; ++i) { s += v[i]; sq += v[i] * v[i]; }
#pragma unroll
  for (int m = 1; m < 64; m <<= 1) { s += __shfl_xor(s, m); sq += __shfl_xor(sq, m); }
  const float mu = s * (1.f / 512.f);
  const float iv = rsqrtf(sq * (1.f / 512.f) - mu * mu + LN_EPS);
  const float4 g0 = ld4(g + lane * 8), g1 = ld4(g + lane * 8 + 4);
  const float4 b0 = ld4(bb + lane * 8), b1 = ld4(bb + lane * 8 + 4);
  const float gg[8] = {g0.x, g0.y, g0.z, g0.w, g1.x, g1.y, g1.z, g1.w};
  const float bbv[8] = {b0.x, b0.y, b0.z, b0.w, b1.x, b1.y, b1.z, b1.w};
  float o[8], osq[8];
#pragma unroll
  for (int i = 0; i < 8; ++i) {
    o[i] = (v[i] - mu) * iv * gg[i] + bbv[i];
    osq[i] = o[i] * o[i];
  }
  *(uint4*)(dst + (long)row * 512 + lane * 8) = pack8(o);
  *(uint4*)(dstsq + (long)row * 512 + lane * 8) = pack8(osq);
}

// ===========================================================================
// prep: lh-rows (w1, c2/c3/c4) + bl-rows (A96 [g | g·be | g²], sums)
// ===========================================================================
__global__ __launch_bounds__(256) void prep_k(
    const u16* __restrict__ u_bf, const float* __restrict__ gam, const float* __restrict__ bet,
    const float* __restrict__ g2, const float* __restrict__ b2,
    u16* __restrict__ w1, float* __restrict__ c2, float* __restrict__ c3, float* __restrict__ c4,
    u16* __restrict__ A96, float* __restrict__ sum_be, float* __restrict__ sum_be2) {
  const int bid = blockIdx.x, t = threadIdx.x, lane = t & 63;
  const int e = lane * 8;
  if (bid < 1024) {
    const int lh = bid * 4 + (t >> 6);
    const int bl = lh >> 3;
    const uint4 up = *(const uint4*)(u_bf + (long)lh * 512 + e);
    const u16* us = (const u16*)&up;
    const float4 ga0 = ld4(gam + (long)bl * 512 + e), ga1 = ld4(gam + (long)bl * 512 + e + 4);
    const float4 be0 = ld4(bet + (long)bl * 512 + e), be1 = ld4(bet + (long)bl * 512 + e + 4);
    const float4 G0 = ld4(g2 + e), G1 = ld4(g2 + e + 4);
    const float4 B0 = ld4(b2 + e), B1 = ld4(b2 + e + 4);
    const float gv[8] = {ga0.x, ga0.y, ga0.z, ga0.w, ga1.x, ga1.y, ga1.z, ga1.w};
    const float bv[8] = {be0.x, be0.y, be0.z, be0.w, be1.x, be1.y, be1.z, be1.w};
    const float Gv[8] = {G0.x, G0.y, G0.z, G0.w, G1.x, G1.y, G1.z, G1.w};
    const float Bv[8] = {B0.x, B0.y, B0.z, B0.w, B1.x, B1.y, B1.z, B1.w};
    float wv[8]; float a2 = 0.f, a3 = 0.f, a4 = 0.f;
#pragma unroll
    for (int i = 0; i < 8; ++i) {
      const float uu = b2f(us[i]);
      const float t1 = Gv[i] * uu;
      wv[i] = gv[i] * t1;
      a2 += bv[i] * t1; a3 += t1; a4 += Bv[i] * uu;
    }
    *(uint4*)(w1 + (long)lh * 512 + e) = pack8(wv);
#pragma unroll
    for (int m = 1; m < 64; m <<= 1) {
      a2 += __shfl_xor(a2, m); a3 += __shfl_xor(a3, m); a4 += __shfl_xor(a4, m);
    }
    if (lane == 0) { c2[lh] = a2; c3[lh] = a3; c4[lh] = a4; }
  } else {
    const int bl = (bid - 1024) * 4 + (t >> 6);
    const int b = bl >> 5, l = bl & 31;
    const float4 ga0 = ld4(gam + (long)bl * 512 + e), ga1 = ld4(gam + (long)bl * 512 + e + 4);
    const float4 be0 = ld4(bet + (long)bl * 512 + e), be1 = ld4(bet + (long)bl * 512 + e + 4);
    const float gv[8] = {ga0.x, ga0.y, ga0.z, ga0.w, ga1.x, ga1.y, ga1.z, ga1.w};
    const float bv[8] = {be0.x, be0.y, be0.z, be0.w, be1.x, be1.y, be1.z, be1.w};
    float gg[8], gb[8]; float s1 = 0.f, s2 = 0.f;
#pragma unroll
    for (int i = 0; i < 8; ++i) {
      gg[i] = gv[i] * gv[i]; gb[i] = gv[i] * bv[i];
      s1 += bv[i]; s2 += bv[i] * bv[i];
    }
    const long base = ((long)b * 96 + l) * 512 + e;
    *(uint4*)(A96 + base) = pack8(gv);                 // rows  0..31 : g    (vs cb)
    *(uint4*)(A96 + base + 32 * 512) = pack8(gb);      // rows 32..63 : g·be (vs cb)
    *(uint4*)(A96 + base + 64 * 512) = pack8(gg);      // rows 64..95 : g²   (vs cb²)
#pragma unroll
    for (int m = 1; m < 64; m <<= 1) { s1 += __shfl_xor(s1, m); s2 += __shfl_xor(s2, m); }
    if (lane == 0) { sum_be[bl] = s1; sum_be2[bl] = s2; }
  }
}

// ===========================================================================
// softmax over logits rows -> w_bf, W1_bf (=w*iv), S1, S2
// ===========================================================================
__global__ __launch_bounds__(256) void softmax_k(
    const float* __restrict__ logits, const float* __restrict__ P,
    const float* __restrict__ sum_be, const float* __restrict__ sum_be2,
    u16* __restrict__ w_bf, u16* __restrict__ W1_bf,
    float* __restrict__ S1, float* __restrict__ S2) {
  const int lh = blockIdx.x * 4 + (threadIdx.x >> 6);
  const int lane = threadIdx.x & 63;
  const int b = lh >> 8, l = (lh >> 3) & 31, bl = lh >> 3;
  const int e = lane * 4;
  const float4 lg = ld4(logits + (long)lh * 256 + e);
  const float* Pb = P + ((long)b * 96 + l) * 256 + e;
  const float4 p0 = ld4(Pb), pgb = ld4(Pb + 32 * 256), pg2 = ld4(Pb + 64 * 256);
  const float sbe = sum_be[bl], sbe2 = sum_be2[bl];
  const float lgs[4] = {lg.x, lg.y, lg.z, lg.w};
  const float p0s[4] = {p0.x, p0.y, p0.z, p0.w};
  const float pgbs[4] = {pgb.x, pgb.y, pgb.z, pgb.w};
  const float pg2s[4] = {pg2.x, pg2.y, pg2.z, pg2.w};
  float mu[4], iv[4];
#pragma unroll
  for (int i = 0; i < 4; ++i) {
    mu[i] = (p0s[i] + sbe) * (1.f / 512.f);
    const float msq = (pg2s[i] + 2.f * pgbs[i] + sbe2) * (1.f / 512.f);
    iv[i] = rsqrtf(msq - mu[i] * mu[i] + LN_EPS);
  }
  float mx = fmaxf(fmaxf(lgs[0], lgs[1]), fmaxf(lgs[2], lgs[3]));
#pragma unroll
  for (int m = 1; m < 64; m <<= 1) mx = fmaxf(mx, __shfl_xor(mx, m));
  float ex[4]; float z = 0.f;
#pragma unroll
  for (int i = 0; i < 4; ++i) { ex[i] = expf(lgs[i] - mx); z += ex[i]; }
#pragma unroll
  for (int m = 1; m < 64; m <<= 1) z += __shfl_xor(z, m);
  const float rz = 1.f / z;
  float wv[4], w1v[4]; float s1 = 0.f, s2 = 0.f;
#pragma unroll
  for (int i = 0; i < 4; ++i) {
    wv[i] = ex[i] * rz;
    w1v[i] = wv[i] * iv[i];
    s1 += w1v[i]; s2 += w1v[i] * mu[i];
  }
  uint2 wp, w1p;
  wp.x = pk2(wv[0], wv[1]); wp.y = pk2(wv[2], wv[3]);
  w1p.x = pk2(w1v[0], w1v[1]); w1p.y = pk2(w1v[2], w1v[3]);
  *(uint2*)(w_bf + (long)lh * 256 + e) = wp;
  *(uint2*)(W1_bf + (long)lh * 256 + e) = w1p;
#pragma unroll
  for (int m = 1; m < 64; m <<= 1) { s1 += __shfl_xor(s1, m); s2 += __shfl_xor(s2, m); }
  if (lane == 0) { S1[lh] = s1; S2[lh] = s2; }
}

// ===========================================================================
// ============== Fallback path (round-1 verified kernels) ===================
// ===========================================================================
template <int ROWS, int POST>
__global__ __launch_bounds__(256) void proj_kernel(
    const float* __restrict__ X, const float* __restrict__ W,
    const float* __restrict__ bias,
    float* __restrict__ out0, float* __restrict__ out1,
    int C_total, int cols_per_block) {
  __shared__ float Xs[ROWS][Dm];
  const int r0 = blockIdx.x * ROWS;
  const int tid = threadIdx.x;
  for (int i = tid; i < ROWS * Dm; i += 256)
    Xs[i / Dm][i % Dm] = X[(size_t)(r0 + i / Dm) * Dm + (i % Dm)];
  __syncthreads();
  const int j0 = blockIdx.y * cols_per_block;
  for (int j = j0 + tid; j < j0 + cols_per_block; j += 256) {
    float acc[ROWS];
#pragma unroll
    for (int r = 0; r < ROWS; ++r) acc[r] = 0.f;
    const float* wrow = W + (size_t)j * Dm;
    for (int d = 0; d < Dm; d += 4) {
      const float4 w = ld4(wrow + d);
#pragma unroll
      for (int r = 0; r < ROWS; ++r)
        acc[r] += Xs[r][d] * w.x + Xs[r][d + 1] * w.y + Xs[r][d + 2] * w.z + Xs[r][d + 3] * w.w;
    }
    const float bb = bias ? bias[j] : 0.f;
#pragma unroll
    for (int r = 0; r < ROWS; ++r) {
      float v = acc[r] + bb;
      if (POST == 1) {
        v = tanhf(v);
        const int Ch = C_total >> 1;
        if (j < Ch) out0[(size_t)(r0 + r) * Ch + j] = v;
        else        out1[(size_t)(r0 + r) * Ch + (j - Ch)] = v;
      } else {
        out0[(size_t)(r0 + r) * C_total + j] = v;
      }
    }
  }
}

__global__ __launch_bounds__(256) void lnproj_kernel(
    const float* __restrict__ X, const float* __restrict__ W,
    const float* __restrict__ bias, const float* __restrict__ lng,
    const float* __restrict__ lnb, float* __restrict__ out) {
  constexpr int ROWS = 8;
  __shared__ float Xs[ROWS][Dm];
  __shared__ float Ys[ROWS][Dm];
  const int r0 = blockIdx.x * ROWS;
  const int tid = threadIdx.x;
  for (int i = tid; i < ROWS * Dm; i += 256)
    Xs[i / Dm][i % Dm] = X[(size_t)(r0 + i / Dm) * Dm + (i % Dm)];
  __syncthreads();
#pragma unroll
  for (int cc = 0; cc < 2; ++cc) {
    const int j = cc * 256 + tid;
    float acc[ROWS];
#pragma unroll
    for (int r = 0; r < ROWS; ++r) acc[r] = 0.f;
    const float* wrow = W + (size_t)j * Dm;
    for (int d = 0; d < Dm; d += 4) {
      const float4 w = ld4(wrow + d);
#pragma unroll
      for (int r = 0; r < ROWS; ++r)
        acc[r] += Xs[r][d] * w.x + Xs[r][d + 1] * w.y + Xs[r][d + 2] * w.z + Xs[r][d + 3] * w.w;
    }
    const float bb = bias[j];
#pragma unroll
    for (int r = 0; r < ROWS; ++r) Ys[r][j] = acc[r] + bb;
  }
  __syncthreads();
  const int wave = tid >> 6, lane = tid & 63;
  for (int r = wave; r < ROWS; r += 4) {
    float vals[8];
    float s = 0.f, sq = 0.f;
#pragma unroll
    for (int i = 0; i < 8; ++i) {
      const float v = Ys[r][lane + 64 * i];
      vals[i] = v; s += v; sq += v * v;
    }
#pragma unroll
    for (int m = 1; m < 64; m <<= 1) { s += __shfl_xor(s, m); sq += __shfl_xor(sq, m); }
    const float mu = s * (1.f / Dm);
    const float iv = rsqrtf(sq * (1.f / Dm) - mu * mu + LN_EPS);
#pragma unroll
    for (int i = 0; i < 8; ++i) {
      const int e2 = lane + 64 * i;
      out[(size_t)(r0 + r) * Dm + e2] = (vals[i] - mu) * iv * lng[e2] + lnb[e2];
    }
  }
}

__global__ __launch_bounds__(256) void u_kernel(
    const float* __restrict__ qh, const float* __restrict__ Wk,
    float* __restrict__ u) {
  __shared__ float Xs[16][64];
  const int r0 = blockIdx.x * 16;
  const int h = blockIdx.y;
  const int tid = threadIdx.x;
  for (int i = tid; i < 16 * 64; i += 256)
    Xs[i >> 6][i & 63] = qh[(size_t)(r0 + (i >> 6)) * Dm + h * 64 + (i & 63)];
  __syncthreads();
#pragma unroll
  for (int cc = 0; cc < 2; ++cc) {
    const int j = cc * 256 + tid;
    float acc[16];
#pragma unroll
    for (int r = 0; r < 16; ++r) acc[r] = 0.f;
    for (int c = 0; c < 64; ++c) {
      const float wv = Wk[(size_t)(h * 64 + c) * Dm + j];
#pragma unroll
      for (int r = 0; r < 16; ++r) acc[r] += Xs[r][c] * wv;
    }
#pragma unroll
    for (int r = 0; r < 16; ++r)
      u[((size_t)(r0 + r) * Hn + h) * Dm + j] = acc[r] * 0.125f;
  }
}

__global__ __launch_bounds__(256) void main_kernel(
    const float* __restrict__ gam, const float* __restrict__ bet,
    const float* __restrict__ cond_base, const float* __restrict__ kin,
    const float* __restrict__ ln2g, const float* __restrict__ ln2b,
    const float* __restrict__ u, float* __restrict__ sout) {
  __shared__ float w_s[Hn][LKn];
  __shared__ float mu_s[LKn], iv_s[LKn];
  __shared__ float s_s[Hn][Dm];
  const int bl = blockIdx.x;
  const int b = bl >> 5;
  const int tid = threadIdx.x, wave = tid >> 6, lane = tid & 63;
  const int d0 = lane * 4, d1 = 256 + lane * 4;

  for (int i = tid; i < Hn * Dm; i += 256) s_s[i >> 9][i & 511] = 0.f;

  const float4 g0 = ld4(gam + (size_t)bl * Dm + d0), g1 = ld4(gam + (size_t)bl * Dm + d1);
  const float4 be0 = ld4(bet + (size_t)bl * Dm + d0), be1 = ld4(bet + (size_t)bl * Dm + d1);
  const float4 G0 = ld4(ln2g + d0), G1 = ld4(ln2g + d1);
  const float4 Bb0 = ld4(ln2b + d0), Bb1 = ld4(ln2b + d1);
  float4 u0[Hn], u1[Hn];
#pragma unroll
  for (int h = 0; h < Hn; ++h) {
    u0[h] = ld4(u + ((size_t)bl * Hn + h) * Dm + d0);
    u1[h] = ld4(u + ((size_t)bl * Hn + h) * Dm + d1);
  }
  __syncthreads();

  const float* cb = cond_base + (size_t)b * LKn * Dm;
  const float* kb = kin + (size_t)b * LKn * Dm;

  for (int kk = wave * 64; kk < wave * 64 + 64; ++kk) {
    const float* crow = cb + (size_t)kk * Dm;
    const float* krow = kb + (size_t)kk * Dm;
    const float4 c0 = ld4(crow + d0), c1 = ld4(crow + d1);
    const float4 t0 = f4_fma(g0, c0, be0);
    const float4 t1 = f4_fma(g1, c1, be1);
    float ssum = f4_hsum(t0) + f4_hsum(t1);
    float ssq = f4_dot(t0, t0) + f4_dot(t1, t1);
#pragma unroll
    for (int m = 1; m < 64; m <<= 1) { ssum += __shfl_xor(ssum, m); ssq += __shfl_xor(ssq, m); }
    const float mu = ssum * (1.f / Dm);
    const float iv = rsqrtf(ssq * (1.f / Dm) - mu * mu + LN_EPS);
    if (lane == 0) { mu_s[kk] = mu; iv_s[kk] = iv; }
    const float4 k0 = ld4(krow + d0), k1 = ld4(krow + d1);
    const float4 y0 = f4_add(f4_fma(f4_muls(f4_subs(t0, mu), iv), G0, Bb0), k0);
    const float4 y1 = f4_add(f4_fma(f4_muls(f4_subs(t1, mu), iv), G1, Bb1), k1);
    float p[Hn];
#pragma unroll
    for (int h = 0; h < Hn; ++h) p[h] = f4_dot(y0, u0[h]) + f4_dot(y1, u1[h]);
#pragma unroll
    for (int m = 1; m < 64; m <<= 1) {
#pragma unroll
      for (int h = 0; h < Hn; ++h) p[h] += __shfl_xor(p[h], m);
    }
    if (lane < Hn) w_s[lane][kk] = p[lane];
  }
  __syncthreads();

  for (int h = wave; h < Hn; h += 4) {
    float v0 = w_s[h][lane], v1 = w_s[h][64 + lane], v2 = w_s[h][128 + lane], v3 = w_s[h][192 + lane];
    float mx = fmaxf(fmaxf(v0, v1), fmaxf(v2, v3));
#pragma unroll
    for (int m = 1; m < 64; m <<= 1) mx = fmaxf(mx, __shfl_xor(mx, m));
    const float e0 = __expf(v0 - mx), e1 = __expf(v1 - mx), e2 = __expf(v2 - mx), e3 = __expf(v3 - mx);
    float zs = (e0 + e1) + (e2 + e3);
#pragma unroll
    for (int m = 1; m < 64; m <<= 1) zs += __shfl_xor(zs, m);
    const float rz = 1.f / zs;
    w_s[h][lane] = e0 * rz; w_s[h][64 + lane] = e1 * rz;
    w_s[h][128 + lane] = e2 * rz; w_s[h][192 + lane] = e3 * rz;
  }
  __syncthreads();

  float4 a0[Hn], a1[Hn];
#pragma unroll
  for (int h = 0; h < Hn; ++h) {
    a0[h] = make_float4(0.f, 0.f, 0.f, 0.f);
    a1[h] = make_float4(0.f, 0.f, 0.f, 0.f);
  }
  for (int kk = wave * 64; kk < wave * 64 + 64; ++kk) {
    const float* crow = cb + (size_t)kk * Dm;
    const float* krow = kb + (size_t)kk * Dm;
    const float4 c0 = ld4(crow + d0), c1 = ld4(crow + d1);
    const float4 k0 = ld4(krow + d0), k1 = ld4(krow + d1);
    const float mu = mu_s[kk], iv = iv_s[kk];
    const float4 t0 = f4_fma(g0, c0, be0);
    const float4 t1 = f4_fma(g1, c1, be1);
    const float4 y0 = f4_add(f4_fma(f4_muls(f4_subs(t0, mu), iv), G0, Bb0), k0);
    const float4 y1 = f4_add(f4_fma(f4_muls(f4_subs(t1, mu), iv), G1, Bb1), k1);
#pragma unroll
    for (int h = 0; h < Hn; ++h) {
      const float wh = w_s[h][kk];
      a0[h].x = fmaf(wh, y0.x, a0[h].x); a0[h].y = fmaf(wh, y0.y, a0[h].y);
      a0[h].z = fmaf(wh, y0.z, a0[h].z); a0[h].w = fmaf(wh, y0.w, a0[h].w);
      a1[h].x = fmaf(wh, y1.x, a1[h].x); a1[h].y = fmaf(wh, y1.y, a1[h].y);
      a1[h].z = fmaf(wh, y1.z, a1[h].z); a1[h].w = fmaf(wh, y1.w, a1[h].w);
    }
  }
  for (int w = 0; w < 4; ++w) {
    if (wave == w) {
#pragma unroll
      for (int h = 0; h < Hn; ++h) {
        st4(&s_s[h][d0], f4_add(ld4(&s_s[h][d0]), a0[h]));
        st4(&s_s[h][d1], f4_add(ld4(&s_s[h][d1]), a1[h]));
      }
    }
    __syncthreads();
  }
  for (int i = tid; i < Hn * Dm; i += 256)
    sout[(size_t)bl * Hn * Dm + i] = s_s[i >> 9][i & 511];
}

__global__ __launch_bounds__(256) void attnproj_kernel(
    const float* __restrict__ sbuf, const float* __restrict__ Wv,
    float* __restrict__ attn) {
  __shared__ float Xs[16][Dm];
  const int r0 = blockIdx.x * 16, h = blockIdx.y, tid = threadIdx.x;
  for (int i = tid; i < 16 * Dm; i += 256)
    Xs[i >> 9][i & 511] = sbuf[((size_t)(r0 + (i >> 9)) * Hn + h) * Dm + (i & 511)];
  __syncthreads();
  const int j = tid & 63, rg = tid >> 6;
  float acc[4] = {0.f, 0.f, 0.f, 0.f};
  const float* wrow = Wv + (size_t)(h * 64 + j) * Dm;
  for (int d = 0; d < Dm; d += 4) {
    const float4 w = ld4(wrow + d);
#pragma unroll
    for (int rr = 0; rr < 4; ++rr) {
      const int r = rg * 4 + rr;
      acc[rr] += Xs[r][d] * w.x + Xs[r][d + 1] * w.y + Xs[r][d + 2] * w.z + Xs[r][d + 3] * w.w;
    }
  }
#pragma unroll
  for (int rr = 0; rr < 4; ++rr)
    attn[(size_t)(r0 + rg * 4 + rr) * Dm + h * 64 + j] = acc[rr];
}

}  // namespace

extern "C" void kernel_launch(void* const* d_in, const int* in_sizes, int n_in,
                              void* d_out, int out_size, void* d_ws, size_t ws_size,
                              hipStream_t stream) {
  (void)in_sizes; (void)n_in; (void)out_size;
  const float* q    = (const float*)d_in[0];
  const float* k    = (const float*)d_in[1];
  const float* Wq   = (const float*)d_in[3];
  const float* Wk   = (const float*)d_in[4];
  const float* Wv   = (const float*)d_in[5];
  const float* Wfc  = (const float*)d_in[6];
  const float* Wg   = (const float*)d_in[7];
  const float* bg   = (const float*)d_in[8];
  const float* Wvp  = (const float*)d_in[9];
  const float* bvp  = (const float*)d_in[10];
  const float* ln1g = (const float*)d_in[11];
  const float* ln1b = (const float*)d_in[12];
  const float* ln2g = (const float*)d_in[13];
  const float* ln2b = (const float*)d_in[14];
  float* out = (float*)d_out;

  // ---- new-path workspace layout (bump allocator, identical to round 3) ----
  char* base = (char*)d_ws;
  size_t off = 0;
  auto au16 = [&](size_t n) -> u16* {
    u16* p = (u16*)(base + off); off = (off + n * 2 + 255) & ~(size_t)255; return p;
  };
  auto af32 = [&](size_t n) -> float* {
    float* p = (float*)(base + off); off = (off + n * 4 + 255) & ~(size_t)255; return p;
  };
  u16* q_bf    = au16(262144);
  u16* Wg_bf   = au16(524288);
  u16* Wq_bf   = au16(262144);
  u16* Wvp_bf  = au16(262144);
  u16* WkT_bf  = au16(262144);
  u16* Wv_bf   = au16(262144);
  u16* Wfc_bf  = au16(262144);
  u16* k_bf    = au16(2097152);
  u16* kT_bf   = au16(2097152);
  u16* qh_bf   = au16(262144);
  float* gam   = af32(262144);
  float* bet   = af32(262144);
  float* condpre = af32(2097152);
  u16* cb_bf   = au16(2097152);
  u16* cbT_bf  = au16(2097152);
  u16* u_bf    = au16(2097152);
  u16* w1_bf   = au16(2097152);
  float* c2    = af32(4096);
  float* c3    = af32(4096);
  float* c4    = af32(4096);
  u16* A96_bf  = au16(16 * 96 * 512);
  float* sum_be  = af32(512);
  float* sum_be2 = af32(512);
  float* P     = af32(16 * 96 * 256);
  float* sbuf  = af32(1048576);     // s_bf lives here (was K1 slot)
  float* logits = af32(1048576);    // aliased as cbsq_bf until GK writes logits
  u16* w_bf    = au16(1048576);
  u16* W1_bf   = au16(1048576);
  float* S1    = af32(4096);
  float* S2    = af32(4096);
  u16* attn_bf = au16(262144);
  const size_t need_new = off;
  u16* s_bf = (u16*)sbuf;
  u16* cbsq_bf = (u16*)logits;

  const dim3 blk(256);

  if (ws_size >= need_new) {
    // ---------------- factorized bf16-MFMA pipeline (14 dispatches) ----------------
    CopyArgs ca;
    ca.src[0] = q;   ca.dst[0] = q_bf;
    ca.src[1] = Wg;  ca.dst[1] = Wg_bf;
    ca.src[2] = Wq;  ca.dst[2] = Wq_bf;
    ca.src[3] = Wvp; ca.dst[3] = Wvp_bf;
    ca.src[4] = Wv;  ca.dst[4] = Wv_bf;
    ca.src[5] = Wfc; ca.dst[5] = Wfc_bf;
    ca.src[6] = k;   ca.dst[6] = k_bf;
    const int nb[7] = {128, 256, 128, 128, 128, 128, 1024};
    int cum = 0;
    for (int i = 0; i < 7; ++i) { ca.cumb[i] = cum; cum += nb[i]; }
    ca.cumb[7] = cum;  // 1920
    ca.Wk = Wk; ca.WkT = WkT_bf; ca.kf = k; ca.kT = kT_bf;
    prep_inputs_k<<<dim3(cum + 64 + 512), blk, 0, stream>>>(ca);

    GA a = {};
    // G1a: film = tanh(q@Wg^T + bg) -> gam/bet
    a.A = q_bf; a.lda = 512; a.B = Wg_bf; a.ldb = 512;
    a.Cf = gam; a.Cf2 = bet; a.ldc = 512; a.M = 512; a.K = 512; a.e0 = bg;
    gemm_k<2><<<dim3(8, 16, 1), blk, 0, stream>>>(a);
    // G1b: qh_bf = q@Wq^T
    a = {}; a.A = q_bf; a.lda = 512; a.B = Wq_bf; a.ldb = 512;
    a.Cb = qh_bf; a.ldc = 512; a.M = 512; a.K = 512;
    gemm_k<1><<<dim3(8, 8, 1), blk, 0, stream>>>(a);
    // G2: condpre = k@Wvp^T + bvp
    a = {}; a.A = k_bf; a.lda = 512; a.B = Wvp_bf; a.ldb = 512;
    a.Cf = condpre; a.ldc = 512; a.M = 4096; a.K = 512; a.e0 = bvp;
    gemm_k<4><<<dim3(64, 8, 1), blk, 0, stream>>>(a);
    // E2: LN1 -> cb_bf + cbsq_bf
    ln_k<<<dim3(1024), blk, 0, stream>>>(condpre, ln1g, ln1b, cb_bf, cbsq_bf);
    // E2b: cbT
    tp_bf16_k<<<dim3(512), blk, 0, stream>>>(cb_bf, cbT_bf);
    // Gu: u = 0.125 * qh_h @ Wk_h  (per-h)
    a = {}; a.A = qh_bf; a.lda = 512; a.sAz = 64; a.B = WkT_bf; a.ldb = 512; a.sBz = 64;
    a.Cb = u_bf; a.ldc = 512; a.M = 512; a.K = 64;
    gemm_k<5><<<dim3(8, 8, 8), blk, 0, stream>>>(a);
    // E3: w1, c2/c3/c4, A96 (g | g·be | g²), sums
    prep_k<<<dim3(1152), blk, 0, stream>>>(u_bf, gam, bet, ln2g, ln2b,
                                           w1_bf, c2, c3, c4, A96_bf, sum_be, sum_be2);
    // GP: P = A96 @ {cb | cb²}^T (per-b), B-select at row-block 64
    a = {}; a.A = A96_bf; a.lda = 512; a.sAz = 96 * 512;
    a.B = cb_bf; a.Balt = cbsq_bf; a.ldb = 512; a.sBz = 256 * 512;
    a.Cf = P; a.ldc = 256; a.sCz = 96 * 256; a.M = 96; a.K = 512;
    gemm_k<0><<<dim3(2, 4, 16), blk, 0, stream>>>(a);
    // GK: K1 = u@k^T, K2 = w1@cb^T fused, logits epilogue
    GA2 d = {};
    d.A1 = u_bf; d.A2 = w1_bf; d.B1 = k_bf; d.B2 = cb_bf;
    d.lda = 512; d.ldb = 512; d.sAz = 256 * 512; d.sBz = 256 * 512;
    d.Cf = logits; d.ldc = 256; d.sCz = 256 * 256; d.M = 256; d.K = 512;
    d.e1 = P; d.e2 = sum_be; d.e3 = sum_be2; d.e4 = c2; d.e5 = c3; d.e6 = c4;
    gemm2_k<0><<<dim3(4, 4, 16), blk, 0, stream>>>(d);
    // E4: softmax -> w_bf, W1_bf, S1, S2
    softmax_k<<<dim3(1024), blk, 0, stream>>>(logits, P, sum_be, sum_be2,
                                              w_bf, W1_bf, S1, S2);
    // GT: T1 = w@kT^T, T2 = W1@cbT^T fused, s epilogue -> s_bf
    d = {};
    d.A1 = w_bf; d.A2 = W1_bf; d.B1 = kT_bf; d.B2 = cbT_bf;
    d.lda = 256; d.ldb = 256; d.sAz = 256 * 256; d.sBz = 512 * 256;
    d.Cb = s_bf; d.ldc = 512; d.sCz = 256 * 512; d.M = 256; d.K = 256;
    d.e1 = ln2g; d.e2 = ln2b; d.e3 = gam; d.e4 = bet; d.e5 = S1; d.e6 = S2;
    gemm2_k<1><<<dim3(4, 8, 16), blk, 0, stream>>>(d);
    // G8: attn = s_h @ Wv_h^T (per-h)
    a = {}; a.A = s_bf; a.lda = 4096; a.sAz = 512;
    a.B = Wv_bf; a.ldb = 512; a.sBz = 64 * 512;
    a.Cb = attn_bf; a.ldc = 512; a.sCz = 64; a.M = 512; a.K = 512;
    gemm_k<1><<<dim3(8, 1, 8), blk, 0, stream>>>(a);
    // G9: out = attn @ Wfc^T (f32)
    a = {}; a.A = attn_bf; a.lda = 512; a.B = Wfc_bf; a.ldb = 512;
    a.Cf = out; a.ldc = 512; a.M = 512; a.K = 512;
    gemm_k<0><<<dim3(8, 8, 1), blk, 0, stream>>>(a);
  } else {
    // ---------------- fallback: round-1 verified path ----------------
    float* ws = (float*)d_ws;
    const size_t NG = (size_t)NBL * Dm;
    float* gammas    = ws;
    float* betas     = gammas + NG;
    float* qh        = betas + NG;
    float* attn      = qh + NG;
    float* cond_base = attn + NG;
    float* u         = cond_base + (size_t)NBK * Dm;
    float* s         = u + (size_t)NBL * Hn * Dm;
    const size_t need_old = ((size_t)(s + (size_t)NBL * Hn * Dm - ws)) * sizeof(float);
    if (ws_size < need_old) return;

    proj_kernel<8, 1><<<dim3(NBL / 8, 4), blk, 0, stream>>>(q, Wg, bg, gammas, betas, 2 * Dm, 256);
    lnproj_kernel<<<dim3(NBK / 8), blk, 0, stream>>>(k, Wvp, bvp, ln1g, ln1b, cond_base);
    proj_kernel<8, 0><<<dim3(NBL / 8, 2), blk, 0, stream>>>(q, Wq, nullptr, qh, nullptr, Dm, 256);
    u_kernel<<<dim3(NBL / 16, Hn), blk, 0, stream>>>(qh, Wk, u);
    main_kernel<<<dim3(NBL), blk, 0, stream>>>(gammas, betas, cond_base, k, ln2g, ln2b, u, s);
    attnproj_kernel<<<dim3(NBL / 16, Hn), blk, 0, stream>>>(s, Wv, attn);
    proj_kernel<8, 0><<<dim3(NBL / 8, 2), blk, 0, stream>>>(attn, Wfc, nullptr, out, nullptr, Dm, 256);
  }
}

// Round 5
// 93.797 us; speedup vs baseline: 3.9990x; 1.1356x over previous
//
#include <hip/hip_runtime.h>
#include <math.h>

namespace {
constexpr int Dm  = 512;
constexpr int Bn  = 16;
constexpr int LQn = 32;
constexpr int LKn = 256;
constexpr int Hn  = 8;
constexpr int NBL = Bn * LQn;  // 512
constexpr int NBK = Bn * LKn;  // 4096
constexpr float LN_EPS = 1e-5f;

typedef unsigned short u16;
typedef __attribute__((ext_vector_type(8))) short bh8;
typedef __attribute__((ext_vector_type(4))) float fv4;

__device__ __forceinline__ float4 ld4(const float* p) { return *reinterpret_cast<const float4*>(p); }
__device__ __forceinline__ void st4(float* p, float4 v) { *reinterpret_cast<float4*>(p) = v; }
__device__ __forceinline__ float4 f4_fma(float4 a, float4 b, float4 c) {
  return make_float4(fmaf(a.x, b.x, c.x), fmaf(a.y, b.y, c.y), fmaf(a.z, b.z, c.z), fmaf(a.w, b.w, c.w));
}
__device__ __forceinline__ float4 f4_add(float4 a, float4 b) {
  return make_float4(a.x + b.x, a.y + b.y, a.z + b.z, a.w + b.w);
}
__device__ __forceinline__ float4 f4_subs(float4 a, float s) {
  return make_float4(a.x - s, a.y - s, a.z - s, a.w - s);
}
__device__ __forceinline__ float4 f4_muls(float4 a, float s) {
  return make_float4(a.x * s, a.y * s, a.z * s, a.w * s);
}
__device__ __forceinline__ float f4_hsum(float4 a) { return (a.x + a.y) + (a.z + a.w); }
__device__ __forceinline__ float f4_dot(float4 a, float4 b) {
  return fmaf(a.x, b.x, fmaf(a.y, b.y, fmaf(a.z, b.z, a.w * b.w)));
}

__device__ __forceinline__ float b2f(u16 x) {
  union { float f; unsigned u; } c; c.u = ((unsigned)x) << 16; return c.f;
}
__device__ __forceinline__ u16 f2b(float f) {  // RTN-even
  union { float f; unsigned u; } c; c.f = f;
  unsigned u = c.u;
  u += 0x7FFFu + ((u >> 16) & 1u);
  return (u16)(u >> 16);
}
__device__ __forceinline__ unsigned pk2(float a, float b) {
  return (unsigned)f2b(a) | ((unsigned)f2b(b) << 16);
}
__device__ __forceinline__ uint4 pack8(const float* v) {
  uint4 r; r.x = pk2(v[0], v[1]); r.y = pk2(v[2], v[3]); r.z = pk2(v[4], v[5]); r.w = pk2(v[6], v[7]);
  return r;
}

// XOR-swizzled LDS tile access: [64][64] u16, 16B slots, c8 ^= row&7
__device__ __forceinline__ bh8 lds_rd(const u16* S, int row, int c8) {
  return *(const bh8*)&S[row * 64 + ((c8 ^ (row & 7)) << 3)];
}

// ===========================================================================
// Generic batched bf16 MFMA GEMM core: C[z][r][c] = sum_k A[z][r][k]*B[z][c][k]
// 64x64 tile, BK=64, 4 waves (2x2 of 32x32), swizzled LDS, reg prefetch.
// Runtime epilogue select (epi): 0 f32, 1 bf16, 2 film, 4 +bias f32, 5 u-remap
// ===========================================================================
struct GA {
  const u16* A; const u16* B; const u16* Balt;
  long lda, ldb, sAz, sBz;
  float* Cf; u16* Cb; float* Cf2;
  long ldc, sCz;
  int M, K, epi, nx, ny, nz;
  const float* e0;
};

__device__ __forceinline__ void gemm_core(const GA& a, u16* As, u16* Bs,
                                          int bx, int by, int bz, int t) {
  const int z = bz;
  const int bm0 = bx * 64, bn0 = by * 64;
  const int lane = t & 63, w = t >> 6;
  const int wm = (w >> 1) * 32, wn = (w & 1) * 32;
  const u16* Ab = a.A + (long)z * a.sAz;
  const u16* Bbase = (a.Balt != nullptr && bm0 >= 64) ? a.Balt : a.B;
  const u16* Bb = Bbase + (long)z * a.sBz;

  const int sr = t >> 3, sc8 = t & 7, sc = sc8 * 8;
  int ar0 = bm0 + sr;      if (ar0 > a.M - 1) ar0 = a.M - 1;
  int ar1 = bm0 + sr + 32; if (ar1 > a.M - 1) ar1 = a.M - 1;
  const u16* ap0 = Ab + (long)ar0 * a.lda + sc;
  const u16* ap1 = Ab + (long)ar1 * a.lda + sc;
  const u16* bp0 = Bb + (long)(bn0 + sr) * a.ldb + sc;
  const u16* bp1 = Bb + (long)(bn0 + sr + 32) * a.ldb + sc;
  const int iA0 = sr * 64 + ((sc8 ^ (sr & 7)) << 3);
  const int iA1 = iA0 + 32 * 64;

  fv4 zero = {0.f, 0.f, 0.f, 0.f};
  fv4 acc00 = zero, acc01 = zero, acc10 = zero, acc11 = zero;
  const int r0 = lane & 15, kq8 = lane >> 4;
  const int nk = a.K >> 6;

  uint4 av0 = *(const uint4*)ap0, av1 = *(const uint4*)ap1;
  uint4 bv0 = *(const uint4*)bp0, bv1 = *(const uint4*)bp1;
  for (int kt = 0; kt < nk; ++kt) {
    __syncthreads();
    *(uint4*)&As[iA0] = av0; *(uint4*)&As[iA1] = av1;
    *(uint4*)&Bs[iA0] = bv0; *(uint4*)&Bs[iA1] = bv1;
    __syncthreads();
    if (kt + 1 < nk) {
      ap0 += 64; ap1 += 64; bp0 += 64; bp1 += 64;
      av0 = *(const uint4*)ap0; av1 = *(const uint4*)ap1;
      bv0 = *(const uint4*)bp0; bv1 = *(const uint4*)bp1;
    }
#pragma unroll
    for (int kc = 0; kc < 2; ++kc) {
      const int c8 = kq8 + 4 * kc;
      bh8 aa0 = lds_rd(As, wm + r0, c8);
      bh8 aa1 = lds_rd(As, wm + 16 + r0, c8);
      bh8 bb0 = lds_rd(Bs, wn + r0, c8);
      bh8 bb1 = lds_rd(Bs, wn + 16 + r0, c8);
      acc00 = __builtin_amdgcn_mfma_f32_16x16x32_bf16(aa0, bb0, acc00, 0, 0, 0);
      acc01 = __builtin_amdgcn_mfma_f32_16x16x32_bf16(aa0, bb1, acc01, 0, 0, 0);
      acc10 = __builtin_amdgcn_mfma_f32_16x16x32_bf16(aa1, bb0, acc10, 0, 0, 0);
      acc11 = __builtin_amdgcn_mfma_f32_16x16x32_bf16(aa1, bb1, acc11, 0, 0, 0);
    }
  }

  fv4 accs[2][2] = {{acc00, acc01}, {acc10, acc11}};
#pragma unroll
  for (int rb = 0; rb < 2; ++rb) {
#pragma unroll
    for (int cbl = 0; cbl < 2; ++cbl) {
#pragma unroll
      for (int j = 0; j < 4; ++j) {
        const int r = bm0 + wm + rb * 16 + (lane >> 4) * 4 + j;
        const int c = bn0 + wn + cbl * 16 + (lane & 15);
        if (r >= a.M) continue;
        const float v = accs[rb][cbl][j];
        if (a.epi == 0) {
          a.Cf[(long)z * a.sCz + (long)r * a.ldc + c] = v;
        } else if (a.epi == 1) {
          a.Cb[(long)z * a.sCz + (long)r * a.ldc + c] = f2b(v);
        } else if (a.epi == 2) {  // film
          const float x = tanhf(v + a.e0[c]);
          if (c < 512) a.Cf[(long)r * 512 + c] = x;
          else         a.Cf2[(long)r * 512 + (c - 512)] = x;
        } else if (a.epi == 4) {  // + bias, f32
          a.Cf[(long)r * a.ldc + c] = v + a.e0[c];
        } else {  // 5: u remap, *0.125
          a.Cb[((long)r * 8 + z) * a.ldc + c] = f2b(v * 0.125f);
        }
      }
    }
  }
}

struct MG { GA g[3]; int cum[4]; };

__global__ __launch_bounds__(256) void mgemm_k(MG m) {
  __shared__ u16 As[64 * 64];
  __shared__ u16 Bs[64 * 64];
  const int bid = blockIdx.x, t = threadIdx.x;
  int i = 0;
  while (i < 2 && bid >= m.cum[i + 1]) ++i;
  const GA& a = m.g[i];
  const int rel = bid - m.cum[i];
  const int bx = rel % a.nx;
  const int rest = rel / a.nx;
  const int by = rest % a.ny;
  const int bz = rest / a.ny;
  gemm_core(a, As, Bs, bx, by, bz, t);
}

// ===========================================================================
// Dual batched GEMM (GK / GT) — unchanged from round 4 (verified)
// ===========================================================================
struct GA2 {
  const u16* A1; const u16* A2; const u16* B1; const u16* B2;
  long lda, ldb, sAz, sBz;
  float* Cf; u16* Cb;
  long ldc, sCz;
  int M, K;
  const float* e1; const float* e2; const float* e3;
  const float* e4; const float* e5; const float* e6;
};

template <int EPI>
__global__ __launch_bounds__(256) void gemm2_k(GA2 a) {
  __shared__ u16 As1[64 * 64];
  __shared__ u16 As2[64 * 64];
  __shared__ u16 Bs1[64 * 64];
  __shared__ u16 Bs2[64 * 64];
  const int z = blockIdx.z;
  const int bm0 = blockIdx.x * 64, bn0 = blockIdx.y * 64;
  const int t = threadIdx.x, lane = t & 63, w = t >> 6;
  const int wm = (w >> 1) * 32, wn = (w & 1) * 32;
  const u16* A1b = a.A1 + (long)z * a.sAz;
  const u16* A2b = a.A2 + (long)z * a.sAz;
  const u16* B1b = a.B1 + (long)z * a.sBz;
  const u16* B2b = a.B2 + (long)z * a.sBz;

  const int sr = t >> 3, sc8 = t & 7, sc = sc8 * 8;
  const long aoff0 = (long)(bm0 + sr) * a.lda + sc;
  const long aoff1 = (long)(bm0 + sr + 32) * a.lda + sc;
  const long boff0 = (long)(bn0 + sr) * a.ldb + sc;
  const long boff1 = (long)(bn0 + sr + 32) * a.ldb + sc;
  const u16 *a1p0 = A1b + aoff0, *a1p1 = A1b + aoff1;
  const u16 *a2p0 = A2b + aoff0, *a2p1 = A2b + aoff1;
  const u16 *b1p0 = B1b + boff0, *b1p1 = B1b + boff1;
  const u16 *b2p0 = B2b + boff0, *b2p1 = B2b + boff1;
  const int iA0 = sr * 64 + ((sc8 ^ (sr & 7)) << 3);
  const int iA1 = iA0 + 32 * 64;

  fv4 zero = {0.f, 0.f, 0.f, 0.f};
  fv4 p00 = zero, p01 = zero, p10 = zero, p11 = zero;
  fv4 q00 = zero, q01 = zero, q10 = zero, q11 = zero;
  const int r0 = lane & 15, kq8 = lane >> 4;
  const int nk = a.K >> 6;

  uint4 a1v0 = *(const uint4*)a1p0, a1v1 = *(const uint4*)a1p1;
  uint4 a2v0 = *(const uint4*)a2p0, a2v1 = *(const uint4*)a2p1;
  uint4 b1v0 = *(const uint4*)b1p0, b1v1 = *(const uint4*)b1p1;
  uint4 b2v0 = *(const uint4*)b2p0, b2v1 = *(const uint4*)b2p1;
  for (int kt = 0; kt < nk; ++kt) {
    __syncthreads();
    *(uint4*)&As1[iA0] = a1v0; *(uint4*)&As1[iA1] = a1v1;
    *(uint4*)&As2[iA0] = a2v0; *(uint4*)&As2[iA1] = a2v1;
    *(uint4*)&Bs1[iA0] = b1v0; *(uint4*)&Bs1[iA1] = b1v1;
    *(uint4*)&Bs2[iA0] = b2v0; *(uint4*)&Bs2[iA1] = b2v1;
    __syncthreads();
    if (kt + 1 < nk) {
      a1p0 += 64; a1p1 += 64; a2p0 += 64; a2p1 += 64;
      b1p0 += 64; b1p1 += 64; b2p0 += 64; b2p1 += 64;
      a1v0 = *(const uint4*)a1p0; a1v1 = *(const uint4*)a1p1;
      a2v0 = *(const uint4*)a2p0; a2v1 = *(const uint4*)a2p1;
      b1v0 = *(const uint4*)b1p0; b1v1 = *(const uint4*)b1p1;
      b2v0 = *(const uint4*)b2p0; b2v1 = *(const uint4*)b2p1;
    }
#pragma unroll
    for (int kc = 0; kc < 2; ++kc) {
      const int c8 = kq8 + 4 * kc;
      bh8 x0 = lds_rd(As1, wm + r0, c8);
      bh8 x1 = lds_rd(As1, wm + 16 + r0, c8);
      bh8 y0 = lds_rd(Bs1, wn + r0, c8);
      bh8 y1 = lds_rd(Bs1, wn + 16 + r0, c8);
      p00 = __builtin_amdgcn_mfma_f32_16x16x32_bf16(x0, y0, p00, 0, 0, 0);
      p01 = __builtin_amdgcn_mfma_f32_16x16x32_bf16(x0, y1, p01, 0, 0, 0);
      p10 = __builtin_amdgcn_mfma_f32_16x16x32_bf16(x1, y0, p10, 0, 0, 0);
      p11 = __builtin_amdgcn_mfma_f32_16x16x32_bf16(x1, y1, p11, 0, 0, 0);
      bh8 u0 = lds_rd(As2, wm + r0, c8);
      bh8 u1 = lds_rd(As2, wm + 16 + r0, c8);
      bh8 v0 = lds_rd(Bs2, wn + r0, c8);
      bh8 v1 = lds_rd(Bs2, wn + 16 + r0, c8);
      q00 = __builtin_amdgcn_mfma_f32_16x16x32_bf16(u0, v0, q00, 0, 0, 0);
      q01 = __builtin_amdgcn_mfma_f32_16x16x32_bf16(u0, v1, q01, 0, 0, 0);
      q10 = __builtin_amdgcn_mfma_f32_16x16x32_bf16(u1, v0, q10, 0, 0, 0);
      q11 = __builtin_amdgcn_mfma_f32_16x16x32_bf16(u1, v1, q11, 0, 0, 0);
    }
  }

  fv4 pa[2][2] = {{p00, p01}, {p10, p11}};
  fv4 qa[2][2] = {{q00, q01}, {q10, q11}};
#pragma unroll
  for (int rb = 0; rb < 2; ++rb) {
#pragma unroll
    for (int cbl = 0; cbl < 2; ++cbl) {
#pragma unroll
      for (int j = 0; j < 4; ++j) {
        const int r = bm0 + wm + rb * 16 + (lane >> 4) * 4 + j;
        const int c = bn0 + wn + cbl * 16 + (lane & 15);
        if (r >= a.M) continue;
        const float v1 = pa[rb][cbl][j];
        const float v2 = qa[rb][cbl][j];
        if (EPI == 0) {  // logits: v1=K1, v2=K2
          const int l = r >> 3;
          const int lh = z * 256 + r;
          const int bl = z * 32 + l;
          const float* Pb = a.e1 + ((long)z * 96 + l) * 256 + c;
          const float P0 = Pb[0], Pgb = Pb[32 * 256], Pg2 = Pb[64 * 256];
          const float mu = (P0 + a.e2[bl]) * (1.f / 512.f);
          const float msq = (Pg2 + 2.f * Pgb + a.e3[bl]) * (1.f / 512.f);
          const float iv = rsqrtf(msq - mu * mu + LN_EPS);
          const float lg = v1 + a.e6[lh] + iv * (v2 + a.e4[lh] - mu * a.e5[lh]);
          a.Cf[(long)z * a.sCz + (long)r * a.ldc + c] = lg;
        } else {  // s: v1=T1, v2=T2
          const int lh = z * 256 + r;
          const int bl = z * 32 + (r >> 3);
          const float G2d = a.e1[c], B2d = a.e2[c];
          const float gv = a.e3[(long)bl * 512 + c];
          const float bev = a.e4[(long)bl * 512 + c];
          const float sv = v1 + B2d + G2d * (gv * v2 + bev * a.e5[lh] - a.e6[lh]);
          a.Cb[(long)z * a.sCz + (long)r * a.ldc + c] = f2b(sv);
        }
      }
    }
  }
}

// ===========================================================================
// prep_inputs: f32->bf16 copies + f32->bf16 transposes (WkT, kT)
// ===========================================================================
struct CopyArgs {
  const float* src[7];
  u16* dst[7];
  int cumb[8];
  const float* Wk; u16* WkT;
  const float* kf; u16* kT;
};

__device__ __forceinline__ void tp_core_f32(const float* src, long lds, u16* dst, long ldd,
                                            int tr, int tc, int t, float T[64][65]) {
  const int c = t & 63, rg = t >> 6;
#pragma unroll 4
  for (int i = 0; i < 16; ++i) {
    const int r = rg + 4 * i;
    T[r][c] = src[(long)(tr * 64 + r) * lds + tc * 64 + c];
  }
  __syncthreads();
#pragma unroll 4
  for (int i = 0; i < 16; ++i) {
    const int r = rg + 4 * i;
    dst[(long)(tc * 64 + r) * ldd + tr * 64 + c] = f2b(T[c][r]);
  }
}

__global__ __launch_bounds__(256) void prep_inputs_k(CopyArgs ca) {
  __shared__ float T[64][65];
  const int bid = blockIdx.x, t = threadIdx.x;
  if (bid < ca.cumb[7]) {
    int i = 0;
    while (bid >= ca.cumb[i + 1]) ++i;
    const long idx = (long)(bid - ca.cumb[i]) * 2048 + t * 8;
    const float* s = ca.src[i] + idx;
    const float4 x0 = ld4(s), x1 = ld4(s + 4);
    const float v[8] = {x0.x, x0.y, x0.z, x0.w, x1.x, x1.y, x1.z, x1.w};
    *(uint4*)(ca.dst[i] + idx) = pack8(v);
  } else if (bid < ca.cumb[7] + 64) {
    const int tt = bid - ca.cumb[7];
    tp_core_f32(ca.Wk, 512, ca.WkT, 512, tt >> 3, tt & 7, t, T);
  } else {
    const int tt = bid - ca.cumb[7] - 64;
    const int b = tt >> 5, w32 = tt & 31;
    tp_core_f32(ca.kf + (long)b * 131072, 512, ca.kT + (long)b * 131072, 256,
                w32 >> 3, w32 & 7, t, T);
  }
}

// ===========================================================================
// D3: routed LN1 (cb, cb²) + A96/sums
// ===========================================================================
__global__ __launch_bounds__(256) void ln_a96_k(
    const float* __restrict__ src, const float* __restrict__ g1,
    const float* __restrict__ b1,
    u16* __restrict__ dst, u16* __restrict__ dstsq,
    const float* __restrict__ gam, const float* __restrict__ bet,
    u16* __restrict__ A96, float* __restrict__ sum_be, float* __restrict__ sum_be2) {
  const int bid = blockIdx.x, t = threadIdx.x, lane = t & 63;
  const int e = lane * 8;
  if (bid < 1024) {
    // LN over condpre rows
    const int row = bid * 4 + (t >> 6);
    const float* p = src + (long)row * 512 + e;
    const float4 x0 = ld4(p), x1 = ld4(p + 4);
    float v[8] = {x0.x, x0.y, x0.z, x0.w, x1.x, x1.y, x1.z, x1.w};
    float s = 0.f, sq = 0.f;
#pragma unroll
    for (int i = 0; i < 8; ++i) { s += v[i]; sq += v[i] * v[i]; }
#pragma unroll
    for (int m = 1; m < 64; m <<= 1) { s += __shfl_xor(s, m); sq += __shfl_xor(sq, m); }
    const float mu = s * (1.f / 512.f);
    const float iv = rsqrtf(sq * (1.f / 512.f) - mu * mu + LN_EPS);
    const float4 g0 = ld4(g1 + e), g1v = ld4(g1 + e + 4);
    const float4 b0 = ld4(b1 + e), b1v = ld4(b1 + e + 4);
    const float gg[8] = {g0.x, g0.y, g0.z, g0.w, g1v.x, g1v.y, g1v.z, g1v.w};
    const float bbv[8] = {b0.x, b0.y, b0.z, b0.w, b1v.x, b1v.y, b1v.z, b1v.w};
    float o[8], osq[8];
#pragma unroll
    for (int i = 0; i < 8; ++i) {
      o[i] = (v[i] - mu) * iv * gg[i] + bbv[i];
      osq[i] = o[i] * o[i];
    }
    *(uint4*)(dst + (long)row * 512 + e) = pack8(o);
    *(uint4*)(dstsq + (long)row * 512 + e) = pack8(osq);
  } else {
    // A96 (g | g·be | g²) + sum_be / sum_be2
    const int bl = (bid - 1024) * 4 + (t >> 6);
    const int b = bl >> 5, l = bl & 31;
    const float4 ga0 = ld4(gam + (long)bl * 512 + e), ga1 = ld4(gam + (long)bl * 512 + e + 4);
    const float4 be0 = ld4(bet + (long)bl * 512 + e), be1 = ld4(bet + (long)bl * 512 + e + 4);
    const float gv[8] = {ga0.x, ga0.y, ga0.z, ga0.w, ga1.x, ga1.y, ga1.z, ga1.w};
    const float bv[8] = {be0.x, be0.y, be0.z, be0.w, be1.x, be1.y, be1.z, be1.w};
    float gg[8], gb[8]; float s1 = 0.f, s2 = 0.f;
#pragma unroll
    for (int i = 0; i < 8; ++i) {
      gg[i] = gv[i] * gv[i]; gb[i] = gv[i] * bv[i];
      s1 += bv[i]; s2 += bv[i] * bv[i];
    }
    const long basei = ((long)b * 96 + l) * 512 + e;
    *(uint4*)(A96 + basei) = pack8(gv);
    *(uint4*)(A96 + basei + 32 * 512) = pack8(gb);
    *(uint4*)(A96 + basei + 64 * 512) = pack8(gg);
#pragma unroll
    for (int m = 1; m < 64; m <<= 1) { s1 += __shfl_xor(s1, m); s2 += __shfl_xor(s2, m); }
    if (lane == 0) { sum_be[bl] = s1; sum_be2[bl] = s2; }
  }
}

// ===========================================================================
// D4: mixed dispatch — Gu (gemm) + GP (gemm) + cbT transpose
// ===========================================================================
struct MX { GA g[2]; int cumA, cumB; const u16* tp_src; u16* tp_dst; };

__global__ __launch_bounds__(256) void mixed_k(MX m) {
  __shared__ u16 As[64 * 64];
  __shared__ u16 Bs[64 * 64];
  __shared__ float T[64][65];
  const int bid = blockIdx.x, t = threadIdx.x;
  if (bid < m.cumB) {
    const int i = (bid < m.cumA) ? 0 : 1;
    const GA& a = m.g[i];
    const int rel = bid - (i ? m.cumA : 0);
    const int bx = rel % a.nx;
    const int rest = rel / a.nx;
    const int by = rest % a.ny;
    const int bz = rest / a.ny;
    gemm_core(a, As, Bs, bx, by, bz, t);
  } else {
    // bf16 transpose cb -> cbT, per-b [256][512] -> [512][256]
    const int tt = bid - m.cumB;
    const int b = tt >> 5, w32 = tt & 31, tr = w32 >> 3, tc = w32 & 7;
    const u16* s = m.tp_src + (long)b * 131072;
    u16* d = m.tp_dst + (long)b * 131072;
    const int c = t & 63, rg = t >> 6;
#pragma unroll 4
    for (int i = 0; i < 16; ++i) {
      const int r = rg + 4 * i;
      T[r][c] = b2f(s[(long)(tr * 64 + r) * 512 + tc * 64 + c]);
    }
    __syncthreads();
#pragma unroll 4
    for (int i = 0; i < 16; ++i) {
      const int r = rg + 4 * i;
      d[(long)(tc * 64 + r) * 256 + tr * 64 + c] = f2b(T[c][r]);
    }
  }
}

// ===========================================================================
// D5: w1 + c2/c3/c4 (from u)
// ===========================================================================
__global__ __launch_bounds__(256) void w1_k(
    const u16* __restrict__ u_bf, const float* __restrict__ gam, const float* __restrict__ bet,
    const float* __restrict__ g2, const float* __restrict__ b2,
    u16* __restrict__ w1, float* __restrict__ c2, float* __restrict__ c3,
    float* __restrict__ c4) {
  const int t = threadIdx.x, lane = t & 63;
  const int e = lane * 8;
  const int lh = blockIdx.x * 4 + (t >> 6);
  const int bl = lh >> 3;
  const uint4 up = *(const uint4*)(u_bf + (long)lh * 512 + e);
  const u16* us = (const u16*)&up;
  const float4 ga0 = ld4(gam + (long)bl * 512 + e), ga1 = ld4(gam + (long)bl * 512 + e + 4);
  const float4 be0 = ld4(bet + (long)bl * 512 + e), be1 = ld4(bet + (long)bl * 512 + e + 4);
  const float4 G0 = ld4(g2 + e), G1 = ld4(g2 + e + 4);
  const float4 B0 = ld4(b2 + e), B1 = ld4(b2 + e + 4);
  const float gv[8] = {ga0.x, ga0.y, ga0.z, ga0.w, ga1.x, ga1.y, ga1.z, ga1.w};
  const float bv[8] = {be0.x, be0.y, be0.z, be0.w, be1.x, be1.y, be1.z, be1.w};
  const float Gv[8] = {G0.x, G0.y, G0.z, G0.w, G1.x, G1.y, G1.z, G1.w};
  const float Bv[8] = {B0.x, B0.y, B0.z, B0.w, B1.x, B1.y, B1.z, B1.w};
  float wv[8]; float a2 = 0.f, a3 = 0.f, a4 = 0.f;
#pragma unroll
  for (int i = 0; i < 8; ++i) {
    const float uu = b2f(us[i]);
    const float t1 = Gv[i] * uu;
    wv[i] = gv[i] * t1;
    a2 += bv[i] * t1; a3 += t1; a4 += Bv[i] * uu;
  }
  *(uint4*)(w1 + (long)lh * 512 + e) = pack8(wv);
#pragma unroll
  for (int m = 1; m < 64; m <<= 1) {
    a2 += __shfl_xor(a2, m); a3 += __shfl_xor(a3, m); a4 += __shfl_xor(a4, m);
  }
  if (lane == 0) { c2[lh] = a2; c3[lh] = a3; c4[lh] = a4; }
}

// ===========================================================================
// softmax over logits rows -> w_bf, W1_bf (=w*iv), S1, S2
// ===========================================================================
__global__ __launch_bounds__(256) void softmax_k(
    const float* __restrict__ logits, const float* __restrict__ P,
    const float* __restrict__ sum_be, const float* __restrict__ sum_be2,
    u16* __restrict__ w_bf, u16* __restrict__ W1_bf,
    float* __restrict__ S1, float* __restrict__ S2) {
  const int lh = blockIdx.x * 4 + (threadIdx.x >> 6);
  const int lane = threadIdx.x & 63;
  const int b = lh >> 8, l = (lh >> 3) & 31, bl = lh >> 3;
  const int e = lane * 4;
  const float4 lg = ld4(logits + (long)lh * 256 + e);
  const float* Pb = P + ((long)b * 96 + l) * 256 + e;
  const float4 p0 = ld4(Pb), pgb = ld4(Pb + 32 * 256), pg2 = ld4(Pb + 64 * 256);
  const float sbe = sum_be[bl], sbe2 = sum_be2[bl];
  const float lgs[4] = {lg.x, lg.y, lg.z, lg.w};
  const float p0s[4] = {p0.x, p0.y, p0.z, p0.w};
  const float pgbs[4] = {pgb.x, pgb.y, pgb.z, pgb.w};
  const float pg2s[4] = {pg2.x, pg2.y, pg2.z, pg2.w};
  float mu[4], iv[4];
#pragma unroll
  for (int i = 0; i < 4; ++i) {
    mu[i] = (p0s[i] + sbe) * (1.f / 512.f);
    const float msq = (pg2s[i] + 2.f * pgbs[i] + sbe2) * (1.f / 512.f);
    iv[i] = rsqrtf(msq - mu[i] * mu[i] + LN_EPS);
  }
  float mx = fmaxf(fmaxf(lgs[0], lgs[1]), fmaxf(lgs[2], lgs[3]));
#pragma unroll
  for (int m = 1; m < 64; m <<= 1) mx = fmaxf(mx, __shfl_xor(mx, m));
  float ex[4]; float z = 0.f;
#pragma unroll
  for (int i = 0; i < 4; ++i) { ex[i] = expf(lgs[i] - mx); z += ex[i]; }
#pragma unroll
  for (int m = 1; m < 64; m <<= 1) z += __shfl_xor(z, m);
  const float rz = 1.f / z;
  float wv[4], w1v[4]; float s1 = 0.f, s2 = 0.f;
#pragma unroll
  for (int i = 0; i < 4; ++i) {
    wv[i] = ex[i] * rz;
    w1v[i] = wv[i] * iv[i];
    s1 += w1v[i]; s2 += w1v[i] * mu[i];
  }
  uint2 wp, w1p;
  wp.x = pk2(wv[0], wv[1]); wp.y = pk2(wv[2], wv[3]);
  w1p.x = pk2(w1v[0], w1v[1]); w1p.y = pk2(w1v[2], w1v[3]);
  *(uint2*)(w_bf + (long)lh * 256 + e) = wp;
  *(uint2*)(W1_bf + (long)lh * 256 + e) = w1p;
#pragma unroll
  for (int m = 1; m < 64; m <<= 1) { s1 += __shfl_xor(s1, m); s2 += __shfl_xor(s2, m); }
  if (lane == 0) { S1[lh] = s1; S2[lh] = s2; }
}

// ===========================================================================
// ============== Fallback path (round-1 verified kernels) ===================
// ===========================================================================
template <int ROWS, int POST>
__global__ __launch_bounds__(256) void proj_kernel(
    const float* __restrict__ X, const float* __restrict__ W,
    const float* __restrict__ bias,
    float* __restrict__ out0, float* __restrict__ out1,
    int C_total, int cols_per_block) {
  __shared__ float Xs[ROWS][Dm];
  const int r0 = blockIdx.x * ROWS;
  const int tid = threadIdx.x;
  for (int i = tid; i < ROWS * Dm; i += 256)
    Xs[i / Dm][i % Dm] = X[(size_t)(r0 + i / Dm) * Dm + (i % Dm)];
  __syncthreads();
  const int j0 = blockIdx.y * cols_per_block;
  for (int j = j0 + tid; j < j0 + cols_per_block; j += 256) {
    float acc[ROWS];
#pragma unroll
    for (int r = 0; r < ROWS; ++r) acc[r] = 0.f;
    const float* wrow = W + (size_t)j * Dm;
    for (int d = 0; d < Dm; d += 4) {
      const float4 w = ld4(wrow + d);
#pragma unroll
      for (int r = 0; r < ROWS; ++r)
        acc[r] += Xs[r][d] * w.x + Xs[r][d + 1] * w.y + Xs[r][d + 2] * w.z + Xs[r][d + 3] * w.w;
    }
    const float bb = bias ? bias[j] : 0.f;
#pragma unroll
    for (int r = 0; r < ROWS; ++r) {
      float v = acc[r] + bb;
      if (POST == 1) {
        v = tanhf(v);
        const int Ch = C_total >> 1;
        if (j < Ch) out0[(size_t)(r0 + r) * Ch + j] = v;
        else        out1[(size_t)(r0 + r) * Ch + (j - Ch)] = v;
      } else {
        out0[(size_t)(r0 + r) * C_total + j] = v;
      }
    }
  }
}

__global__ __launch_bounds__(256) void lnproj_kernel(
    const float* __restrict__ X, const float* __restrict__ W,
    const float* __restrict__ bias, const float* __restrict__ lng,
    const float* __restrict__ lnb, float* __restrict__ out) {
  constexpr int ROWS = 8;
  __shared__ float Xs[ROWS][Dm];
  __shared__ float Ys[ROWS][Dm];
  const int r0 = blockIdx.x * ROWS;
  const int tid = threadIdx.x;
  for (int i = tid; i < ROWS * Dm; i += 256)
    Xs[i / Dm][i % Dm] = X[(size_t)(r0 + i / Dm) * Dm + (i % Dm)];
  __syncthreads();
#pragma unroll
  for (int cc = 0; cc < 2; ++cc) {
    const int j = cc * 256 + tid;
    float acc[ROWS];
#pragma unroll
    for (int r = 0; r < ROWS; ++r) acc[r] = 0.f;
    const float* wrow = W + (size_t)j * Dm;
    for (int d = 0; d < Dm; d += 4) {
      const float4 w = ld4(wrow + d);
#pragma unroll
      for (int r = 0; r < ROWS; ++r)
        acc[r] += Xs[r][d] * w.x + Xs[r][d + 1] * w.y + Xs[r][d + 2] * w.z + Xs[r][d + 3] * w.w;
    }
    const float bb = bias[j];
#pragma unroll
    for (int r = 0; r < ROWS; ++r) Ys[r][j] = acc[r] + bb;
  }
  __syncthreads();
  const int wave = tid >> 6, lane = tid & 63;
  for (int r = wave; r < ROWS; r += 4) {
    float vals[8];
    float s = 0.f, sq = 0.f;
#pragma unroll
    for (int i = 0; i < 8; ++i) {
      const float v = Ys[r][lane + 64 * i];
      vals[i] = v; s += v; sq += v * v;
    }
#pragma unroll
    for (int m = 1; m < 64; m <<= 1) { s += __shfl_xor(s, m); sq += __shfl_xor(sq, m); }
    const float mu = s * (1.f / Dm);
    const float iv = rsqrtf(sq * (1.f / Dm) - mu * mu + LN_EPS);
#pragma unroll
    for (int i = 0; i < 8; ++i) {
      const int e2 = lane + 64 * i;
      out[(size_t)(r0 + r) * Dm + e2] = (vals[i] - mu) * iv * lng[e2] + lnb[e2];
    }
  }
}

__global__ __launch_bounds__(256) void u_kernel(
    const float* __restrict__ qh, const float* __restrict__ Wk,
    float* __restrict__ u) {
  __shared__ float Xs[16][64];
  const int r0 = blockIdx.x * 16;
  const int h = blockIdx.y;
  const int tid = threadIdx.x;
  for (int i = tid; i < 16 * 64; i += 256)
    Xs[i >> 6][i & 63] = qh[(size_t)(r0 + (i >> 6)) * Dm + h * 64 + (i & 63)];
  __syncthreads();
#pragma unroll
  for (int cc = 0; cc < 2; ++cc) {
    const int j = cc * 256 + tid;
    float acc[16];
#pragma unroll
    for (int r = 0; r < 16; ++r) acc[r] = 0.f;
    for (int c = 0; c < 64; ++c) {
      const float wv = Wk[(size_t)(h * 64 + c) * Dm + j];
#pragma unroll
      for (int r = 0; r < 16; ++r) acc[r] += Xs[r][c] * wv;
    }
#pragma unroll
    for (int r = 0; r < 16; ++r)
      u[((size_t)(r0 + r) * Hn + h) * Dm + j] = acc[r] * 0.125f;
  }
}

__global__ __launch_bounds__(256) void main_kernel(
    const float* __restrict__ gam, const float* __restrict__ bet,
    const float* __restrict__ cond_base, const float* __restrict__ kin,
    const float* __restrict__ ln2g, const float* __restrict__ ln2b,
    const float* __restrict__ u, float* __restrict__ sout) {
  __shared__ float w_s[Hn][LKn];
  __shared__ float mu_s[LKn], iv_s[LKn];
  __shared__ float s_s[Hn][Dm];
  const int bl = blockIdx.x;
  const int b = bl >> 5;
  const int tid = threadIdx.x, wave = tid >> 6, lane = tid & 63;
  const int d0 = lane * 4, d1 = 256 + lane * 4;

  for (int i = tid; i < Hn * Dm; i += 256) s_s[i >> 9][i & 511] = 0.f;

  const float4 g0 = ld4(gam + (size_t)bl * Dm + d0), g1 = ld4(gam + (size_t)bl * Dm + d1);
  const float4 be0 = ld4(bet + (size_t)bl * Dm + d0), be1 = ld4(bet + (size_t)bl * Dm + d1);
  const float4 G0 = ld4(ln2g + d0), G1 = ld4(ln2g + d1);
  const float4 Bb0 = ld4(ln2b + d0), Bb1 = ld4(ln2b + d1);
  float4 u0[Hn], u1[Hn];
#pragma unroll
  for (int h = 0; h < Hn; ++h) {
    u0[h] = ld4(u + ((size_t)bl * Hn + h) * Dm + d0);
    u1[h] = ld4(u + ((size_t)bl * Hn + h) * Dm + d1);
  }
  __syncthreads();

  const float* cb = cond_base + (size_t)b * LKn * Dm;
  const float* kb = kin + (size_t)b * LKn * Dm;

  for (int kk = wave * 64; kk < wave * 64 + 64; ++kk) {
    const float* crow = cb + (size_t)kk * Dm;
    const float* krow = kb + (size_t)kk * Dm;
    const float4 c0 = ld4(crow + d0), c1 = ld4(crow + d1);
    const float4 t0 = f4_fma(g0, c0, be0);
    const float4 t1 = f4_fma(g1, c1, be1);
    float ssum = f4_hsum(t0) + f4_hsum(t1);
    float ssq = f4_dot(t0, t0) + f4_dot(t1, t1);
#pragma unroll
    for (int m = 1; m < 64; m <<= 1) { ssum += __shfl_xor(ssum, m); ssq += __shfl_xor(ssq, m); }
    const float mu = ssum * (1.f / Dm);
    const float iv = rsqrtf(ssq * (1.f / Dm) - mu * mu + LN_EPS);
    if (lane == 0) { mu_s[kk] = mu; iv_s[kk] = iv; }
    const float4 k0 = ld4(krow + d0), k1 = ld4(krow + d1);
    const float4 y0 = f4_add(f4_fma(f4_muls(f4_subs(t0, mu), iv), G0, Bb0), k0);
    const float4 y1 = f4_add(f4_fma(f4_muls(f4_subs(t1, mu), iv), G1, Bb1), k1);
    float p[Hn];
#pragma unroll
    for (int h = 0; h < Hn; ++h) p[h] = f4_dot(y0, u0[h]) + f4_dot(y1, u1[h]);
#pragma unroll
    for (int m = 1; m < 64; m <<= 1) {
#pragma unroll
      for (int h = 0; h < Hn; ++h) p[h] += __shfl_xor(p[h], m);
    }
    if (lane < Hn) w_s[lane][kk] = p[lane];
  }
  __syncthreads();

  for (int h = wave; h < Hn; h += 4) {
    float v0 = w_s[h][lane], v1 = w_s[h][64 + lane], v2 = w_s[h][128 + lane], v3 = w_s[h][192 + lane];
    float mx = fmaxf(fmaxf(v0, v1), fmaxf(v2, v3));
#pragma unroll
    for (int m = 1; m < 64; m <<= 1) mx = fmaxf(mx, __shfl_xor(mx, m));
    const float e0 = __expf(v0 - mx), e1 = __expf(v1 - mx), e2 = __expf(v2 - mx), e3 = __expf(v3 - mx);
    float zs = (e0 + e1) + (e2 + e3);
#pragma unroll
    for (int m = 1; m < 64; m <<= 1) zs += __shfl_xor(zs, m);
    const float rz = 1.f / zs;
    w_s[h][lane] = e0 * rz; w_s[h][64 + lane] = e1 * rz;
    w_s[h][128 + lane] = e2 * rz; w_s[h][192 + lane] = e3 * rz;
  }
  __syncthreads();

  float4 a0[Hn], a1[Hn];
#pragma unroll
  for (int h = 0; h < Hn; ++h) {
    a0[h] = make_float4(0.f, 0.f, 0.f, 0.f);
    a1[h] = make_float4(0.f, 0.f, 0.f, 0.f);
  }
  for (int kk = wave * 64; kk < wave * 64 + 64; ++kk) {
    const float* crow = cb + (size_t)kk * Dm;
    const float* krow = kb + (size_t)kk * Dm;
    const float4 c0 = ld4(crow + d0), c1 = ld4(crow + d1);
    const float4 k0 = ld4(krow + d0), k1 = ld4(krow + d1);
    const float mu = mu_s[kk], iv = iv_s[kk];
    const float4 t0 = f4_fma(g0, c0, be0);
    const float4 t1 = f4_fma(g1, c1, be1);
    const float4 y0 = f4_add(f4_fma(f4_muls(f4_subs(t0, mu), iv), G0, Bb0), k0);
    const float4 y1 = f4_add(f4_fma(f4_muls(f4_subs(t1, mu), iv), G1, Bb1), k1);
#pragma unroll
    for (int h = 0; h < Hn; ++h) {
      const float wh = w_s[h][kk];
      a0[h].x = fmaf(wh, y0.x, a0[h].x); a0[h].y = fmaf(wh, y0.y, a0[h].y);
      a0[h].z = fmaf(wh, y0.z, a0[h].z); a0[h].w = fmaf(wh, y0.w, a0[h].w);
      a1[h].x = fmaf(wh, y1.x, a1[h].x); a1[h].y = fmaf(wh, y1.y, a1[h].y);
      a1[h].z = fmaf(wh, y1.z, a1[h].z); a1[h].w = fmaf(wh, y1.w, a1[h].w);
    }
  }
  for (int w = 0; w < 4; ++w) {
    if (wave == w) {
#pragma unroll
      for (int h = 0; h < Hn; ++h) {
        st4(&s_s[h][d0], f4_add(ld4(&s_s[h][d0]), a0[h]));
        st4(&s_s[h][d1], f4_add(ld4(&s_s[h][d1]), a1[h]));
      }
    }
    __syncthreads();
  }
  for (int i = tid; i < Hn * Dm; i += 256)
    sout[(size_t)bl * Hn * Dm + i] = s_s[i >> 9][i & 511];
}

__global__ __launch_bounds__(256) void attnproj_kernel(
    const float* __restrict__ sbuf, const float* __restrict__ Wv,
    float* __restrict__ attn) {
  __shared__ float Xs[16][Dm];
  const int r0 = blockIdx.x * 16, h = blockIdx.y, tid = threadIdx.x;
  for (int i = tid; i < 16 * Dm; i += 256)
    Xs[i >> 9][i & 511] = sbuf[((size_t)(r0 + (i >> 9)) * Hn + h) * Dm + (i & 511)];
  __syncthreads();
  const int j = tid & 63, rg = tid >> 6;
  float acc[4] = {0.f, 0.f, 0.f, 0.f};
  const float* wrow = Wv + (size_t)(h * 64 + j) * Dm;
  for (int d = 0; d < Dm; d += 4) {
    const float4 w = ld4(wrow + d);
#pragma unroll
    for (int rr = 0; rr < 4; ++rr) {
      const int r = rg * 4 + rr;
      acc[rr] += Xs[r][d] * w.x + Xs[r][d + 1] * w.y + Xs[r][d + 2] * w.z + Xs[r][d + 3] * w.w;
    }
  }
#pragma unroll
  for (int rr = 0; rr < 4; ++rr)
    attn[(size_t)(r0 + rg * 4 + rr) * Dm + h * 64 + j] = acc[rr];
}

}  // namespace

extern "C" void kernel_launch(void* const* d_in, const int* in_sizes, int n_in,
                              void* d_out, int out_size, void* d_ws, size_t ws_size,
                              hipStream_t stream) {
  (void)in_sizes; (void)n_in; (void)out_size;
  const float* q    = (const float*)d_in[0];
  const float* k    = (const float*)d_in[1];
  const float* Wq   = (const float*)d_in[3];
  const float* Wk   = (const float*)d_in[4];
  const float* Wv   = (const float*)d_in[5];
  const float* Wfc  = (const float*)d_in[6];
  const float* Wg   = (const float*)d_in[7];
  const float* bg   = (const float*)d_in[8];
  const float* Wvp  = (const float*)d_in[9];
  const float* bvp  = (const float*)d_in[10];
  const float* ln1g = (const float*)d_in[11];
  const float* ln1b = (const float*)d_in[12];
  const float* ln2g = (const float*)d_in[13];
  const float* ln2b = (const float*)d_in[14];
  float* out = (float*)d_out;

  // ---- workspace layout (bump allocator, identical sizes to round 4) ----
  char* base = (char*)d_ws;
  size_t off = 0;
  auto au16 = [&](size_t n) -> u16* {
    u16* p = (u16*)(base + off); off = (off + n * 2 + 255) & ~(size_t)255; return p;
  };
  auto af32 = [&](size_t n) -> float* {
    float* p = (float*)(base + off); off = (off + n * 4 + 255) & ~(size_t)255; return p;
  };
  u16* q_bf    = au16(262144);
  u16* Wg_bf   = au16(524288);
  u16* Wq_bf   = au16(262144);
  u16* Wvp_bf  = au16(262144);
  u16* WkT_bf  = au16(262144);
  u16* Wv_bf   = au16(262144);
  u16* Wfc_bf  = au16(262144);
  u16* k_bf    = au16(2097152);
  u16* kT_bf   = au16(2097152);
  u16* qh_bf   = au16(262144);
  float* gam   = af32(262144);
  float* bet   = af32(262144);
  float* condpre = af32(2097152);
  u16* cb_bf   = au16(2097152);
  u16* cbT_bf  = au16(2097152);
  u16* u_bf    = au16(2097152);
  u16* w1_bf   = au16(2097152);
  float* c2    = af32(4096);
  float* c3    = af32(4096);
  float* c4    = af32(4096);
  u16* A96_bf  = au16(16 * 96 * 512);
  float* sum_be  = af32(512);
  float* sum_be2 = af32(512);
  float* P     = af32(16 * 96 * 256);
  float* sbuf  = af32(1048576);     // s_bf lives here
  float* logits = af32(1048576);    // aliased as cbsq_bf until GK writes logits
  u16* w_bf    = au16(1048576);
  u16* W1_bf   = au16(1048576);
  float* S1    = af32(4096);
  float* S2    = af32(4096);
  u16* attn_bf = au16(262144);
  const size_t need_new = off;
  u16* s_bf = (u16*)sbuf;
  u16* cbsq_bf = (u16*)logits;

  const dim3 blk(256);

  if (ws_size >= need_new) {
    // ---------------- factorized bf16-MFMA pipeline (10 dispatches) ----------------
    // D1: convert + transposes
    CopyArgs ca;
    ca.src[0] = q;   ca.dst[0] = q_bf;
    ca.src[1] = Wg;  ca.dst[1] = Wg_bf;
    ca.src[2] = Wq;  ca.dst[2] = Wq_bf;
    ca.src[3] = Wvp; ca.dst[3] = Wvp_bf;
    ca.src[4] = Wv;  ca.dst[4] = Wv_bf;
    ca.src[5] = Wfc; ca.dst[5] = Wfc_bf;
    ca.src[6] = k;   ca.dst[6] = k_bf;
    const int nb[7] = {128, 256, 128, 128, 128, 128, 1024};
    int cum = 0;
    for (int i = 0; i < 7; ++i) { ca.cumb[i] = cum; cum += nb[i]; }
    ca.cumb[7] = cum;  // 1920
    ca.Wk = Wk; ca.WkT = WkT_bf; ca.kf = k; ca.kT = kT_bf;
    prep_inputs_k<<<dim3(cum + 64 + 512), blk, 0, stream>>>(ca);

    // D2: G2 (512) + G1a (128) + G1b (64) routed into one 704-block dispatch
    MG m2 = {};
    // G2: condpre = k@Wvp^T + bvp
    m2.g[0].A = k_bf; m2.g[0].lda = 512; m2.g[0].B = Wvp_bf; m2.g[0].ldb = 512;
    m2.g[0].Cf = condpre; m2.g[0].ldc = 512; m2.g[0].M = 4096; m2.g[0].K = 512;
    m2.g[0].epi = 4; m2.g[0].nx = 64; m2.g[0].ny = 8; m2.g[0].nz = 1; m2.g[0].e0 = bvp;
    // G1a: film = tanh(q@Wg^T + bg) -> gam/bet
    m2.g[1].A = q_bf; m2.g[1].lda = 512; m2.g[1].B = Wg_bf; m2.g[1].ldb = 512;
    m2.g[1].Cf = gam; m2.g[1].Cf2 = bet; m2.g[1].ldc = 512; m2.g[1].M = 512; m2.g[1].K = 512;
    m2.g[1].epi = 2; m2.g[1].nx = 8; m2.g[1].ny = 16; m2.g[1].nz = 1; m2.g[1].e0 = bg;
    // G1b: qh_bf = q@Wq^T
    m2.g[2].A = q_bf; m2.g[2].lda = 512; m2.g[2].B = Wq_bf; m2.g[2].ldb = 512;
    m2.g[2].Cb = qh_bf; m2.g[2].ldc = 512; m2.g[2].M = 512; m2.g[2].K = 512;
    m2.g[2].epi = 1; m2.g[2].nx = 8; m2.g[2].ny = 8; m2.g[2].nz = 1;
    m2.cum[0] = 0; m2.cum[1] = 512; m2.cum[2] = 640; m2.cum[3] = 704;
    mgemm_k<<<dim3(704), blk, 0, stream>>>(m2);

    // D3: LN1 (1024) + A96/sums (128)
    ln_a96_k<<<dim3(1152), blk, 0, stream>>>(condpre, ln1g, ln1b, cb_bf, cbsq_bf,
                                             gam, bet, A96_bf, sum_be, sum_be2);

    // D4: Gu (512) + GP (128) + cbT transpose (512)
    MX m4 = {};
    // Gu: u = 0.125 * qh_h @ Wk_h (per-h)
    m4.g[0].A = qh_bf; m4.g[0].lda = 512; m4.g[0].sAz = 64;
    m4.g[0].B = WkT_bf; m4.g[0].ldb = 512; m4.g[0].sBz = 64;
    m4.g[0].Cb = u_bf; m4.g[0].ldc = 512; m4.g[0].M = 512; m4.g[0].K = 64;
    m4.g[0].epi = 5; m4.g[0].nx = 8; m4.g[0].ny = 8; m4.g[0].nz = 8;
    // GP: P = A96 @ {cb | cb²}^T (per-b), B-select at row-block 64
    m4.g[1].A = A96_bf; m4.g[1].lda = 512; m4.g[1].sAz = 96 * 512;
    m4.g[1].B = cb_bf; m4.g[1].Balt = cbsq_bf; m4.g[1].ldb = 512; m4.g[1].sBz = 256 * 512;
    m4.g[1].Cf = P; m4.g[1].ldc = 256; m4.g[1].sCz = 96 * 256; m4.g[1].M = 96; m4.g[1].K = 512;
    m4.g[1].epi = 0; m4.g[1].nx = 2; m4.g[1].ny = 4; m4.g[1].nz = 16;
    m4.cumA = 512; m4.cumB = 640;
    m4.tp_src = cb_bf; m4.tp_dst = cbT_bf;
    mixed_k<<<dim3(1152), blk, 0, stream>>>(m4);

    // D5: w1 + c2/c3/c4
    w1_k<<<dim3(1024), blk, 0, stream>>>(u_bf, gam, bet, ln2g, ln2b,
                                         w1_bf, c2, c3, c4);

    // D6: GK — K1 = u@k^T, K2 = w1@cb^T fused, logits epilogue
    GA2 d = {};
    d.A1 = u_bf; d.A2 = w1_bf; d.B1 = k_bf; d.B2 = cb_bf;
    d.lda = 512; d.ldb = 512; d.sAz = 256 * 512; d.sBz = 256 * 512;
    d.Cf = logits; d.ldc = 256; d.sCz = 256 * 256; d.M = 256; d.K = 512;
    d.e1 = P; d.e2 = sum_be; d.e3 = sum_be2; d.e4 = c2; d.e5 = c3; d.e6 = c4;
    gemm2_k<0><<<dim3(4, 4, 16), blk, 0, stream>>>(d);

    // D7: softmax -> w_bf, W1_bf, S1, S2
    softmax_k<<<dim3(1024), blk, 0, stream>>>(logits, P, sum_be, sum_be2,
                                              w_bf, W1_bf, S1, S2);

    // D8: GT — T1 = w@kT^T, T2 = W1@cbT^T fused, s epilogue -> s_bf
    d = {};
    d.A1 = w_bf; d.A2 = W1_bf; d.B1 = kT_bf; d.B2 = cbT_bf;
    d.lda = 256; d.ldb = 256; d.sAz = 256 * 256; d.sBz = 512 * 256;
    d.Cb = s_bf; d.ldc = 512; d.sCz = 256 * 512; d.M = 256; d.K = 256;
    d.e1 = ln2g; d.e2 = ln2b; d.e3 = gam; d.e4 = bet; d.e5 = S1; d.e6 = S2;
    gemm2_k<1><<<dim3(4, 8, 16), blk, 0, stream>>>(d);

    // D9: attn = s_h @ Wv_h^T (per-h)
    MG m9 = {};
    m9.g[0].A = s_bf; m9.g[0].lda = 4096; m9.g[0].sAz = 512;
    m9.g[0].B = Wv_bf; m9.g[0].ldb = 512; m9.g[0].sBz = 64 * 512;
    m9.g[0].Cb = attn_bf; m9.g[0].ldc = 512; m9.g[0].sCz = 64; m9.g[0].M = 512; m9.g[0].K = 512;
    m9.g[0].epi = 1; m9.g[0].nx = 8; m9.g[0].ny = 1; m9.g[0].nz = 8;
    m9.cum[0] = 0; m9.cum[1] = 64; m9.cum[2] = 64; m9.cum[3] = 64;
    mgemm_k<<<dim3(64), blk, 0, stream>>>(m9);

    // D10: out = attn @ Wfc^T (f32)
    MG m10 = {};
    m10.g[0].A = attn_bf; m10.g[0].lda = 512; m10.g[0].B = Wfc_bf; m10.g[0].ldb = 512;
    m10.g[0].Cf = out; m10.g[0].ldc = 512; m10.g[0].M = 512; m10.g[0].K = 512;
    m10.g[0].epi = 0; m10.g[0].nx = 8; m10.g[0].ny = 8; m10.g[0].nz = 1;
    m10.cum[0] = 0; m10.cum[1] = 64; m10.cum[2] = 64; m10.cum[3] = 64;
    mgemm_k<<<dim3(64), blk, 0, stream>>>(m10);
  } else {
    // ---------------- fallback: round-1 verified path ----------------
    float* ws = (float*)d_ws;
    const size_t NG = (size_t)NBL * Dm;
    float* gammas    = ws;
    float* betas     = gammas + NG;
    float* qh        = betas + NG;
    float* attn      = qh + NG;
    float* cond_base = attn + NG;
    float* u         = cond_base + (size_t)NBK * Dm;
    float* s         = u + (size_t)NBL * Hn * Dm;
    const size_t need_old = ((size_t)(s + (size_t)NBL * Hn * Dm - ws)) * sizeof(float);
    if (ws_size < need_old) return;

    proj_kernel<8, 1><<<dim3(NBL / 8, 4), blk, 0, stream>>>(q, Wg, bg, gammas, betas, 2 * Dm, 256);
    lnproj_kernel<<<dim3(NBK / 8), blk, 0, stream>>>(k, Wvp, bvp, ln1g, ln1b, cond_base);
    proj_kernel<8, 0><<<dim3(NBL / 8, 2), blk, 0, stream>>>(q, Wq, nullptr, qh, nullptr, Dm, 256);
    u_kernel<<<dim3(NBL / 16, Hn), blk, 0, stream>>>(qh, Wk, u);
    main_kernel<<<dim3(NBL), blk, 0, stream>>>(gammas, betas, cond_base, k, ln2g, ln2b, u, s);
    attnproj_kernel<<<dim3(NBL / 16, Hn), blk, 0, stream>>>(s, Wv, attn);
    proj_kernel<8, 0><<<dim3(NBL / 8, 2), blk, 0, stream>>>(attn, Wfc, nullptr, out, nullptr, Dm, 256);
  }
}